// Round 9
// baseline (703.082 us; speedup 1.0000x reference)
//
#include <hip/hip_runtime.h>
#include <hip/hip_bf16.h>

#define EPS 1e-5f

typedef __attribute__((ext_vector_type(8))) short bf16x8;
typedef __attribute__((ext_vector_type(4))) float f32x4;
typedef __attribute__((ext_vector_type(4))) float float4v;

__device__ __forceinline__ float b2f(short u) {
    union { unsigned int i; float f; } x;
    x.i = ((unsigned int)(unsigned short)u) << 16;
    return x.f;
}
__device__ __forceinline__ short f2b(float f) {
    unsigned int x = __builtin_bit_cast(unsigned int, f);
    unsigned int r = (x + 0x7FFFu + ((x >> 16) & 1u)) >> 16;
    return (short)r;
}

__device__ __forceinline__ void load_lds16(const void* g, void* l) {
    __builtin_amdgcn_global_load_lds(
        (const __attribute__((address_space(1))) unsigned int*)g,
        (__attribute__((address_space(3))) unsigned int*)l, 16, 0, 0);
}

// ---------------- fused weight prep: 5 big casts + w2 cast + bias concat -----

__device__ __forceinline__ void cast8(const float* __restrict__ src, short* __restrict__ dst, long idx) {
    const float4v* s = (const float4v*)src;
    float4v a = s[idx * 2], b = s[idx * 2 + 1];
    bf16x8 o;
    o[0] = f2b(a[0]); o[1] = f2b(a[1]); o[2] = f2b(a[2]); o[3] = f2b(a[3]);
    o[4] = f2b(b[0]); o[5] = f2b(b[1]); o[6] = f2b(b[2]); o[7] = f2b(b[3]);
    *(bf16x8*)(dst + idx * 8) = o;
}

__global__ __launch_bounds__(256) void k_prep(
    const float* __restrict__ wq, const float* __restrict__ wk, const float* __restrict__ wv,
    const float* __restrict__ wo, const float* __restrict__ wff, const float* __restrict__ w2,
    const float* __restrict__ bq, const float* __restrict__ bk, const float* __restrict__ bv,
    short* __restrict__ Wqkvb, short* __restrict__ wo_b, short* __restrict__ wff_b,
    short* __restrict__ w2_b, float* __restrict__ bqkv) {
    int bid = blockIdx.x, tid = threadIdx.x;
    if (bid < 640) {
        int seg = bid >> 7;
        long idx = (long)(bid & 127) * 256 + tid;
        const float* src;
        short* dst;
        if (seg == 0) { src = wq; dst = Wqkvb; }
        else if (seg == 1) { src = wk; dst = Wqkvb + 262144; }
        else if (seg == 2) { src = wv; dst = Wqkvb + 524288; }
        else if (seg == 3) { src = wo; dst = wo_b; }
        else { src = wff; dst = wff_b; }
        cast8(src, dst, idx);
    } else if (bid < 672) {
        long idx = (long)(bid - 640) * 256 + tid;
        cast8(w2, w2_b, idx);
    } else {
        int i = (bid - 672) * 256 + tid;
        if (i < 512) bqkv[i] = bq[i];
        else if (i < 1024) bqkv[i] = bk[i - 512];
        else if (i < 1536) bqkv[i] = bv[i - 1024];
    }
}

// fused: per-column stats of x [16384,512] + bf16 cast. block = 64 rows.
__global__ __launch_bounds__(256) void k_statcast_x(const float* __restrict__ x,
                                                    short* __restrict__ xb,
                                                    float* __restrict__ psum, float* __restrict__ psq) {
    int b = blockIdx.x, tid = threadIdx.x;
    const float* xp = x + (long)b * 64 * 512;
    short* xo = xb + (long)b * 64 * 512;
    float s0 = 0, q0 = 0, s1 = 0, q1 = 0;
    for (int r = 0; r < 64; ++r) {
        float v0 = xp[r * 512 + tid];
        float v1 = xp[r * 512 + tid + 256];
        xo[r * 512 + tid] = f2b(v0);
        xo[r * 512 + tid + 256] = f2b(v1);
        s0 += v0; q0 += v0 * v0; s1 += v1; q1 += v1 * v1;
    }
    psum[b * 512 + tid] = s0; psum[b * 512 + tid + 256] = s1;
    psq[b * 512 + tid] = q0;  psq[b * 512 + tid + 256] = q1;
}

// ---- parallel finalize: grid = ncols/64, block = 4 part-groups x 64 cols ----

__global__ __launch_bounds__(256) void k_finalize_meanrs(const float* __restrict__ psum,
                                                         const float* __restrict__ psq,
                                                         int nparts, int ncols, float invB,
                                                         float* __restrict__ mean, float* __restrict__ rs) {
    int l = threadIdx.x & 63, grp = threadIdx.x >> 6;
    int c = blockIdx.x * 64 + l;
    float s = 0, q = 0;
    for (int p = grp; p < nparts; p += 4) {
        s += psum[(long)p * ncols + c];
        q += psq[(long)p * ncols + c];
    }
    __shared__ float rs_[4][64], rq_[4][64];
    rs_[grp][l] = s; rq_[grp][l] = q;
    __syncthreads();
    if (grp == 0) {
        s = rs_[0][l] + rs_[1][l] + rs_[2][l] + rs_[3][l];
        q = rq_[0][l] + rq_[1][l] + rq_[2][l] + rq_[3][l];
        float m = s * invB;
        float v = q * invB - m * m;
        mean[c] = m;
        rs[c] = rsqrtf(v + EPS);
    }
}

__global__ __launch_bounds__(256) void k_finalize_ss(const float* __restrict__ psum,
                                                     const float* __restrict__ psq,
                                                     int nparts, int ncols, float invB,
                                                     const float* __restrict__ g, const float* __restrict__ bb,
                                                     float* __restrict__ scale, float* __restrict__ shift) {
    int l = threadIdx.x & 63, grp = threadIdx.x >> 6;
    int c = blockIdx.x * 64 + l;
    float s = 0, q = 0;
    for (int p = grp; p < nparts; p += 4) {
        s += psum[(long)p * ncols + c];
        q += psq[(long)p * ncols + c];
    }
    __shared__ float rs_[4][64], rq_[4][64];
    rs_[grp][l] = s; rq_[grp][l] = q;
    __syncthreads();
    if (grp == 0) {
        s = rs_[0][l] + rs_[1][l] + rs_[2][l] + rs_[3][l];
        q = rq_[0][l] + rq_[1][l] + rq_[2][l] + rq_[3][l];
        float m = s * invB, v = q * invB - m * m;
        float sc = g[c] * rsqrtf(v + EPS);
        scale[c] = sc;
        shift[c] = bb[c] - m * sc;
    }
}

// fold BN1 into w1: block = one (d,o) row
__global__ __launch_bounds__(256) void k_fold_w1(const float* __restrict__ w1, const float* __restrict__ g1,
                                                 const float* __restrict__ b1, const float* __restrict__ mean,
                                                 const float* __restrict__ rs,
                                                 short* __restrict__ W1b, float* __restrict__ beff) {
    int bx = blockIdx.x;  // d*512 + o
    int d = bx >> 9, tid = threadIdx.x;
    const float* wrow = w1 + (long)bx * 512;
    float part = 0.f;
    for (int i = tid; i < 512; i += 256) {
        float wv = wrow[i];
        float sc = rs[i] * g1[d * 512 + i];
        W1b[(long)bx * 512 + i] = f2b(wv * sc);
        part += (b1[d * 512 + i] - mean[i] * sc) * wv;
    }
    __shared__ float red[256];
    red[tid] = part;
    __syncthreads();
    for (int st = 128; st > 0; st >>= 1) {
        if (tid < st) red[tid] += red[tid + st];
        __syncthreads();
    }
    if (tid == 0) beff[bx] = red[0];
}

// t = sigmoid(h*scale + shift), bf16, in-place safe (elementwise same-index)
__global__ __launch_bounds__(256) void k_bnsig(const short* h, short* t,
                                               const float* __restrict__ scale,
                                               const float* __restrict__ shift) {
    long i8 = ((long)blockIdx.x * 256 + threadIdx.x) * 8;
    int c0 = (int)(i8 & 2047);
    bf16x8 v = *(const bf16x8*)(h + i8);
    bf16x8 o;
#pragma unroll
    for (int j = 0; j < 8; ++j) {
        float x = b2f(v[j]) * scale[c0 + j] + shift[c0 + j];
        o[j] = f2b(1.f / (1.f + __expf(-x)));
    }
    *(bf16x8*)(t + i8) = o;
}

// LayerNorm over last dim 512, one wave per token; in-place safe
__global__ __launch_bounds__(256) void k_ln(const short* in, short* out,
                                            const float* __restrict__ g, const float* __restrict__ bb) {
    int w = threadIdx.x >> 6, lane = threadIdx.x & 63;
    long row = (long)blockIdx.x * 4 + w;
    const short* rp = in + row * 512;
    bf16x8 v = *(const bf16x8*)(rp + lane * 8);
    float f[8];
    float s = 0.f;
#pragma unroll
    for (int j = 0; j < 8; ++j) { f[j] = b2f(v[j]); s += f[j]; }
#pragma unroll
    for (int m = 1; m < 64; m <<= 1) s += __shfl_xor(s, m, 64);
    float mean = s * (1.f / 512.f);
    float q = 0.f;
#pragma unroll
    for (int j = 0; j < 8; ++j) { float d = f[j] - mean; q += d * d; }
#pragma unroll
    for (int m = 1; m < 64; m <<= 1) q += __shfl_xor(q, m, 64);
    float rs = rsqrtf(q * (1.f / 512.f) + EPS);
    bf16x8 o;
#pragma unroll
    for (int j = 0; j < 8; ++j) {
        int c = lane * 8 + j;
        o[j] = f2b((f[j] - mean) * rs * g[c] + bb[c]);
    }
    *(bf16x8*)(out + row * 512 + lane * 8) = o;
}

// per-feature stats of out_pre [16384,128] f32
__global__ __launch_bounds__(256) void k_stats_o(const float* __restrict__ pre,
                                                 float* __restrict__ psum, float* __restrict__ psq) {
    int b = blockIdx.x, tid = threadIdx.x;
    int c = tid & 127, rh = tid >> 7;
    const float* pp = pre + (long)b * 128 * 128;
    float s = 0, q = 0;
    for (int r = rh; r < 128; r += 2) {
        float v = pp[r * 128 + c];
        s += v; q += v * v;
    }
    psum[(b * 2 + rh) * 128 + c] = s;
    psq[(b * 2 + rh) * 128 + c] = q;
}

__global__ __launch_bounds__(256) void k_bn3sig(const float* __restrict__ pre, float* __restrict__ out,
                                                const float* __restrict__ scale, const float* __restrict__ shift) {
    long i4 = ((long)blockIdx.x * 256 + threadIdx.x) * 4;
    float4v v = *(const float4v*)(pre + i4);
    int c0 = (int)(i4 & 127);
    float4v o;
#pragma unroll
    for (int j = 0; j < 4; ++j) {
        float x = v[j] * scale[c0 + j] + shift[c0 + j];
        o[j] = 1.f / (1.f + __expf(-x));
    }
    *(float4v*)(out + i4) = o;
}

// ---------------- MFMA GEMM: C = A @ W^T (+bias)(+residual) ----------------
// global_load_lds width=16 staging. C/R deliberately NOT __restrict__ — the
// O-proj call writes C in-place over R (same element read-then-written by the
// same thread; output tiles partition (row,col) across blocks).

template <int BM, int BN, int WGM, int WGN, bool ADD_RES, bool OUT_BF16>
__global__ __launch_bounds__(WGM* WGN * 64) void k_gemm_bt(
    const short* __restrict__ A, int a_zoff, int lda,
    const short* __restrict__ W, int w_zoff,
    const float* __restrict__ bias, int bias_zoff,
    short* Cb, float* Cf, int c_zoff, int ldc,
    const short* R, int ldr, int K) {
    constexpr int BK = 32;
    constexpr int WM = BM / WGM, WN = BN / WGN;
    constexpr int AM = WM / 16, AN = WN / 16;
    constexpr int NT = WGM * WGN * 64;
    constexpr int CH = (BM + BN) * (BK / 8);

    __shared__ alignas(16) short Smem[(BM + BN) * BK];

    int tid = threadIdx.x;
    int wave = tid >> 6, lane = tid & 63;
    int wm = (wave % WGM) * WM, wn = (wave / WGM) * WN;
    long m0 = (long)blockIdx.x * BM;
    int n0 = blockIdx.y * BN;
    int z = blockIdx.z;
    const short* Az = A + (long)z * a_zoff;
    const short* Wz = W + (long)z * w_zoff;

    f32x4 acc[AM][AN];
#pragma unroll
    for (int i = 0; i < AM; ++i)
#pragma unroll
        for (int j = 0; j < AN; ++j)
#pragma unroll
            for (int q = 0; q < 4; ++q) acc[i][j][q] = 0.f;

    int fr = lane & 15, ko = (lane >> 4) * 8;

    for (int k0 = 0; k0 < K; k0 += BK) {
#pragma unroll
        for (int c = tid; c < CH; c += NT) {
            int row = c >> 2, koff = (c & 3) * 8;
            const short* g = (row < BM) ? (Az + (m0 + row) * lda + k0 + koff)
                                        : (Wz + (long)(n0 + row - BM) * K + k0 + koff);
            load_lds16(g, (char*)Smem + (size_t)c * 16);
        }
        __syncthreads();
        bf16x8 af[AM], bfr[AN];
#pragma unroll
        for (int i = 0; i < AM; ++i) af[i] = *(const bf16x8*)(&Smem[(wm + i * 16 + fr) * BK + ko]);
#pragma unroll
        for (int j = 0; j < AN; ++j) bfr[j] = *(const bf16x8*)(&Smem[(BM + wn + j * 16 + fr) * BK + ko]);
#pragma unroll
        for (int i = 0; i < AM; ++i)
#pragma unroll
            for (int j = 0; j < AN; ++j)
                acc[i][j] = __builtin_amdgcn_mfma_f32_16x16x32_bf16(af[i], bfr[j], acc[i][j], 0, 0, 0);
        __syncthreads();
    }

    int cr = (lane >> 4) * 4, cc = lane & 15;
#pragma unroll
    for (int i = 0; i < AM; ++i) {
#pragma unroll
        for (int j = 0; j < AN; ++j) {
            int col = n0 + wn + j * 16 + cc;
            float bv = bias ? bias[(long)z * bias_zoff + col] : 0.f;
#pragma unroll
            for (int q = 0; q < 4; ++q) {
                long row = m0 + wm + i * 16 + cr + q;
                float v = acc[i][j][q] + bv;
                if constexpr (ADD_RES) v += b2f(R[row * (long)ldr + col]);
                long idx = row * (long)ldc + (long)z * c_zoff + col;
                if constexpr (OUT_BF16) Cb[idx] = f2b(v);
                else Cf[idx] = v;
            }
        }
    }
}

// ---------------- E1 GEMM with fused BN2 column-stats epilogue ----------------

__global__ __launch_bounds__(256) void k_gemm_e1(
    const short* __restrict__ A, const short* __restrict__ W1, const float* __restrict__ beff,
    short* __restrict__ h, float* __restrict__ psum, float* __restrict__ psq) {
    constexpr int BK = 32;
    __shared__ alignas(16) short Smem[256 * BK];  // 16KB
    __shared__ float cS[2][128], cQ[2][128];

    int tid = threadIdx.x;
    int wave = tid >> 6, lane = tid & 63;
    int wm = (wave & 1) * 64, wn = (wave >> 1) * 64;
    long m0 = (long)blockIdx.x * 128;
    int n0 = blockIdx.y * 128;
    int z = blockIdx.z;
    const short* Wz = W1 + (long)z * 512 * 512;

    f32x4 acc[4][4];
#pragma unroll
    for (int i = 0; i < 4; ++i)
#pragma unroll
        for (int j = 0; j < 4; ++j)
#pragma unroll
            for (int q = 0; q < 4; ++q) acc[i][j][q] = 0.f;

    int fr = lane & 15, ko = (lane >> 4) * 8;

    for (int k0 = 0; k0 < 512; k0 += BK) {
#pragma unroll
        for (int c = tid; c < 1024; c += 256) {
            int row = c >> 2, koff = (c & 3) * 8;
            const short* g = (row < 128) ? (A + (m0 + row) * 512 + k0 + koff)
                                         : (Wz + (long)(n0 + row - 128) * 512 + k0 + koff);
            load_lds16(g, (char*)Smem + (size_t)c * 16);
        }
        __syncthreads();
        bf16x8 af[4], bfr[4];
#pragma unroll
        for (int i = 0; i < 4; ++i) af[i] = *(const bf16x8*)(&Smem[(wm + i * 16 + fr) * BK + ko]);
#pragma unroll
        for (int j = 0; j < 4; ++j) bfr[j] = *(const bf16x8*)(&Smem[(128 + wn + j * 16 + fr) * BK + ko]);
#pragma unroll
        for (int i = 0; i < 4; ++i)
#pragma unroll
            for (int j = 0; j < 4; ++j)
                acc[i][j] = __builtin_amdgcn_mfma_f32_16x16x32_bf16(af[i], bfr[j], acc[i][j], 0, 0, 0);
        __syncthreads();
    }

    int cr = (lane >> 4) * 4, cc = lane & 15;
    float bv[4], colS[4], colQ[4];
#pragma unroll
    for (int j = 0; j < 4; ++j) {
        bv[j] = beff[z * 512 + n0 + wn + j * 16 + cc];
        colS[j] = 0.f; colQ[j] = 0.f;
    }
#pragma unroll
    for (int i = 0; i < 4; ++i)
#pragma unroll
        for (int j = 0; j < 4; ++j)
#pragma unroll
            for (int q = 0; q < 4; ++q) {
                float v = acc[i][j][q] + bv[j];
                acc[i][j][q] = v;
                colS[j] += v; colQ[j] += v * v;
            }
#pragma unroll
    for (int i = 0; i < 4; ++i)
#pragma unroll
        for (int q = 0; q < 4; ++q) {
            long row = m0 + wm + i * 16 + cr + q;
            short* hp = h + row * 2048 + z * 512 + n0 + wn + cc;
#pragma unroll
            for (int j = 0; j < 4; ++j) hp[j * 16] = f2b(acc[i][j][q]);
        }
#pragma unroll
    for (int j = 0; j < 4; ++j) {
        float s = colS[j], qq = colQ[j];
        s += __shfl_xor(s, 16, 64); s += __shfl_xor(s, 32, 64);
        qq += __shfl_xor(qq, 16, 64); qq += __shfl_xor(qq, 32, 64);
        if (lane < 16) { cS[wave & 1][wn + j * 16 + cc] = s; cQ[wave & 1][wn + j * 16 + cc] = qq; }
    }
    __syncthreads();
    if (tid < 128) {
        float S = cS[0][tid] + cS[1][tid];
        float Q = cQ[0][tid] + cQ[1][tid];
        psum[(long)blockIdx.x * 2048 + z * 512 + n0 + tid] = S;
        psq[(long)blockIdx.x * 2048 + z * 512 + n0 + tid] = Q;
    }
}

// ---------------- per-row attention over 4 tokens, 4 heads, hd=128 ----------------
__global__ __launch_bounds__(256) void k_attn(const short* __restrict__ qkv, short* __restrict__ ao) {
    __shared__ alignas(16) short lds[4][4][1544];
    __shared__ float attn_s[4][4][4][4];
    int w = threadIdx.x >> 6, lane = threadIdx.x & 63;
    long n = (long)blockIdx.x * 4 + w;
    const short* src = qkv + n * 4 * 1536;
#pragma unroll
    for (int c = 0; c < 12; ++c) {
        int e = c * 512 + lane * 8;
        *(bf16x8*)(&lds[w][e / 1536][e % 1536]) = *(const bf16x8*)(src + e);
    }
    __syncthreads();
    int h = lane >> 4, a = (lane >> 2) & 3, b = lane & 3;
    const short* qp = &lds[w][a][h * 128];
    const short* kp = &lds[w][b][512 + h * 128];
    float s = 0.f;
#pragma unroll
    for (int j = 0; j < 128; j += 8) {
        bf16x8 qv = *(const bf16x8*)(qp + j);
        bf16x8 kv = *(const bf16x8*)(kp + j);
#pragma unroll
        for (int x = 0; x < 8; ++x) s += b2f(qv[x]) * b2f(kv[x]);
    }
    s *= 0.08838834764831845f;
    float mx = fmaxf(s, __shfl_xor(s, 1, 64));
    mx = fmaxf(mx, __shfl_xor(mx, 2, 64));
    float e = __expf(s - mx);
    float den = e + __shfl_xor(e, 1, 64);
    den += __shfl_xor(den, 2, 64);
    attn_s[w][h][a][b] = e / den;
    __syncthreads();
    int ta = lane >> 4, cg = lane & 15;
#pragma unroll
    for (int hh = 0; hh < 4; ++hh) {
        int c0 = hh * 128 + cg * 8;
        float at0 = attn_s[w][hh][ta][0], at1 = attn_s[w][hh][ta][1];
        float at2 = attn_s[w][hh][ta][2], at3 = attn_s[w][hh][ta][3];
        bf16x8 v0 = *(const bf16x8*)(&lds[w][0][1024 + c0]);
        bf16x8 v1 = *(const bf16x8*)(&lds[w][1][1024 + c0]);
        bf16x8 v2 = *(const bf16x8*)(&lds[w][2][1024 + c0]);
        bf16x8 v3 = *(const bf16x8*)(&lds[w][3][1024 + c0]);
        bf16x8 ov;
#pragma unroll
        for (int j = 0; j < 8; ++j) {
            float val = at0 * b2f(v0[j]) + at1 * b2f(v1[j]) + at2 * b2f(v2[j]) + at3 * b2f(v3[j]);
            ov[j] = f2b(val);
        }
        *(bf16x8*)(ao + (n * 4 + ta) * 512 + c0) = ov;
    }
}

// ---------------- host ----------------

extern "C" void kernel_launch(void* const* d_in, const int* in_sizes, int n_in,
                              void* d_out, int out_size, void* d_ws, size_t ws_size,
                              hipStream_t stream) {
    const float* x = (const float*)d_in[0];
    const float* bn1_g = (const float*)d_in[1];
    const float* bn1_b = (const float*)d_in[2];
    const float* w1 = (const float*)d_in[3];
    const float* bn2_g = (const float*)d_in[4];
    const float* bn2_b = (const float*)d_in[5];
    const float* wq = (const float*)d_in[6];
    const float* bq = (const float*)d_in[7];
    const float* wk = (const float*)d_in[8];
    const float* bk = (const float*)d_in[9];
    const float* wv = (const float*)d_in[10];
    const float* bv = (const float*)d_in[11];
    const float* wo = (const float*)d_in[12];
    const float* bo = (const float*)d_in[13];
    const float* ln1_g = (const float*)d_in[14];
    const float* ln1_b = (const float*)d_in[15];
    const float* wff = (const float*)d_in[16];
    const float* bff = (const float*)d_in[17];
    const float* ln2_g = (const float*)d_in[18];
    const float* ln2_b = (const float*)d_in[19];
    const float* w2 = (const float*)d_in[20];
    const float* bn3_g = (const float*)d_in[21];
    const float* bn3_b = (const float*)d_in[22];
    float* out = (float*)d_out;

    char* ws = (char*)d_ws;
    size_t off = 0;
    auto alloc = [&](size_t bytes) {
        void* p = ws + off;
        off = (off + bytes + 255) & ~(size_t)255;
        return p;
    };

    // ---- fixed allocations (~82 MB) ----
    short* W1b = (short*)alloc(4l * 512 * 512 * 2);
    float* beff = (float*)alloc(4l * 512 * 4);
    short* Wqkvb = (short*)alloc(1536l * 512 * 2);
    float* bqkv = (float*)alloc(1536l * 4);
    short* wo_b = (short*)alloc(512l * 512 * 2);
    short* wff_b = (short*)alloc(512l * 512 * 2);
    short* w2_b = (short*)alloc(4l * 32 * 512 * 2);
    float* mean1 = (float*)alloc(512 * 4);
    float* rs1 = (float*)alloc(512 * 4);
    float* scale2 = (float*)alloc(2048 * 4);
    float* shift2 = (float*)alloc(2048 * 4);
    float* scale3 = (float*)alloc(128 * 4);
    float* shift3 = (float*)alloc(128 * 4);
    float* psum1 = (float*)alloc(256l * 512 * 4);
    float* psq1 = (float*)alloc(256l * 512 * 4);
    float* psum2 = (float*)alloc(128l * 2048 * 4);
    float* psq2 = (float*)alloc(128l * 2048 * 4);
    float* psum3 = (float*)alloc(256l * 128 * 4);
    float* psq3 = (float*)alloc(256l * 128 * 4);
    short* slotA = (short*)alloc(16384l * 2048 * 2);  // h -> t -> a1 (in-place)
    float* out_pre = (float*)alloc(16384l * 128 * 4);

    // ---- chunk arena: qkv + attn + a2 per chunk = NCq*20480 bytes ----
    long NCq = 1024;
    for (long cand = 4096; cand >= 1024; cand >>= 1) {
        if (off + (size_t)cand * 20480 + (1u << 20) <= ws_size) { NCq = cand; break; }
    }
    char* arena = (char*)alloc((size_t)NCq * 20480);
    short* qkv_c = (short*)arena;                              // NCq*12288 B
    short* attn_c = (short*)(arena + (size_t)NCq * 12288);     // NCq*4096 B
    short* a2_c = (short*)(arena + (size_t)NCq * 16384);       // NCq*4096 B
    short* xb = (short*)arena;  // 16 MB needed only before E1; arena >= 20 MB

    dim3 B256(256);

    // prep + x cast/stats
    hipLaunchKernelGGL(k_prep, dim3(678), B256, 0, stream,
                       wq, wk, wv, wo, wff, w2, bq, bk, bv,
                       Wqkvb, wo_b, wff_b, w2_b, bqkv);
    hipLaunchKernelGGL(k_statcast_x, dim3(256), B256, 0, stream, x, xb, psum1, psq1);

    // BN1 finalize + fold into E1 weights
    hipLaunchKernelGGL(k_finalize_meanrs, dim3(8), B256, 0, stream, psum1, psq1, 256, 512,
                       1.f / 16384.f, mean1, rs1);
    hipLaunchKernelGGL(k_fold_w1, dim3(2048), B256, 0, stream, w1, bn1_g, bn1_b, mean1, rs1, W1b, beff);

    // E1 + fused BN2 partial stats (xb in arena; h -> slotA)
    hipLaunchKernelGGL(k_gemm_e1, dim3(128, 4, 4), B256, 0, stream,
                       xb, W1b, beff, slotA, psum2, psq2);

    // BN2 finalize (scale/shift only; sigmoid applied per chunk)
    hipLaunchKernelGGL(k_finalize_ss, dim3(32), B256, 0, stream, psum2, psq2, 128, 2048,
                       1.f / 16384.f, bn2_g, bn2_b, scale2, shift2);

    // ---- chunked middle: every op row-local, producers feed consumers via L3 ----
    long nch = 16384 / NCq;
    for (long c = 0; c < nch; ++c) {
        long r0 = c * NCq;
        short* t_c = slotA + r0 * 2048;        // [NCq*4, 512] token view
        int gx = (int)(NCq * 4 / 128);

        // BN2-sigmoid for this chunk (in-place h -> t), output L3-hot for QKV
        hipLaunchKernelGGL(k_bnsig, dim3((int)NCq), B256, 0, stream, t_c, t_c, scale2, shift2);

        // QKV: [NCq*4,512] @ [1536,512]^T
        hipLaunchKernelGGL((k_gemm_bt<128, 128, 2, 2, false, true>), dim3(gx, 12, 1), B256, 0, stream,
                           t_c, 0, 512, Wqkvb, 0, bqkv, 0,
                           qkv_c, (float*)nullptr, 0, 1536, (const short*)nullptr, 0, 512);

        // attention
        hipLaunchKernelGGL(k_attn, dim3((int)(NCq / 4)), B256, 0, stream, qkv_c, attn_c);

        // O-proj + bias + residual t, written IN-PLACE over t chunk -> a1pre
        hipLaunchKernelGGL((k_gemm_bt<128, 128, 2, 2, true, true>), dim3(gx, 4, 1), B256, 0, stream,
                           attn_c, 0, 512, wo_b, 0, bo, 0,
                           t_c, (float*)nullptr, 0, 512, t_c, 512, 512);

        // LN1 in-place (t_c region = a1)
        hipLaunchKernelGGL(k_ln, dim3((int)NCq), B256, 0, stream, t_c, t_c, ln1_g, ln1_b);

        // FF + bias + residual a1 -> a2_c
        hipLaunchKernelGGL((k_gemm_bt<128, 128, 2, 2, true, true>), dim3(gx, 4, 1), B256, 0, stream,
                           t_c, 0, 512, wff_b, 0, bff, 0,
                           a2_c, (float*)nullptr, 0, 512, t_c, 512, 512);

        // LN2 in-place (a2_c)
        hipLaunchKernelGGL(k_ln, dim3((int)NCq), B256, 0, stream, a2_c, a2_c, ln2_g, ln2_b);

        // E2: per-detector [NCq,512] @ [32,512]^T -> out_pre chunk (f32)
        hipLaunchKernelGGL((k_gemm_bt<128, 32, 4, 1, false, false>), dim3((int)(NCq / 128), 1, 4), B256, 0, stream,
                           a2_c, 512, 2048, w2_b, 32 * 512, (const float*)nullptr, 0,
                           (short*)nullptr, out_pre + r0 * 128, 32, 128, (const short*)nullptr, 0, 512);
    }

    // BN3 + sigmoid -> out
    hipLaunchKernelGGL(k_stats_o, dim3(128), B256, 0, stream, out_pre, psum3, psq3);
    hipLaunchKernelGGL(k_finalize_ss, dim3(2), B256, 0, stream, psum3, psq3, 256, 128,
                       1.f / 16384.f, bn3_g, bn3_b, scale3, shift3);
    hipLaunchKernelGGL(k_bn3sig, dim3(2048), B256, 0, stream, out_pre, out, scale3, shift3);
}

// Round 10
// 646.174 us; speedup vs baseline: 1.0881x; 1.0881x over previous
//
#include <hip/hip_runtime.h>
#include <hip/hip_bf16.h>

#define EPS 1e-5f

typedef __attribute__((ext_vector_type(8))) short bf16x8;
typedef __attribute__((ext_vector_type(4))) float f32x4;
typedef __attribute__((ext_vector_type(4))) float float4v;

__device__ __forceinline__ float b2f(short u) {
    union { unsigned int i; float f; } x;
    x.i = ((unsigned int)(unsigned short)u) << 16;
    return x.f;
}
__device__ __forceinline__ short f2b(float f) {
    unsigned int x = __builtin_bit_cast(unsigned int, f);
    unsigned int r = (x + 0x7FFFu + ((x >> 16) & 1u)) >> 16;
    return (short)r;
}

__device__ __forceinline__ void load_lds16(const void* g, void* l) {
    __builtin_amdgcn_global_load_lds(
        (const __attribute__((address_space(1))) unsigned int*)g,
        (__attribute__((address_space(3))) unsigned int*)l, 16, 0, 0);
}

// ---------------- fused weight prep: 5 big casts + w2 cast + bias concat -----

__device__ __forceinline__ void cast8(const float* __restrict__ src, short* __restrict__ dst, long idx) {
    const float4v* s = (const float4v*)src;
    float4v a = s[idx * 2], b = s[idx * 2 + 1];
    bf16x8 o;
    o[0] = f2b(a[0]); o[1] = f2b(a[1]); o[2] = f2b(a[2]); o[3] = f2b(a[3]);
    o[4] = f2b(b[0]); o[5] = f2b(b[1]); o[6] = f2b(b[2]); o[7] = f2b(b[3]);
    *(bf16x8*)(dst + idx * 8) = o;
}

__global__ __launch_bounds__(256) void k_prep(
    const float* __restrict__ wq, const float* __restrict__ wk, const float* __restrict__ wv,
    const float* __restrict__ wo, const float* __restrict__ wff, const float* __restrict__ w2,
    const float* __restrict__ bq, const float* __restrict__ bk, const float* __restrict__ bv,
    short* __restrict__ Wqkvb, short* __restrict__ wo_b, short* __restrict__ wff_b,
    short* __restrict__ w2_b, float* __restrict__ bqkv) {
    int bid = blockIdx.x, tid = threadIdx.x;
    if (bid < 640) {
        int seg = bid >> 7;
        long idx = (long)(bid & 127) * 256 + tid;
        const float* src;
        short* dst;
        if (seg == 0) { src = wq; dst = Wqkvb; }
        else if (seg == 1) { src = wk; dst = Wqkvb + 262144; }
        else if (seg == 2) { src = wv; dst = Wqkvb + 524288; }
        else if (seg == 3) { src = wo; dst = wo_b; }
        else { src = wff; dst = wff_b; }
        cast8(src, dst, idx);
    } else if (bid < 672) {
        long idx = (long)(bid - 640) * 256 + tid;
        cast8(w2, w2_b, idx);
    } else {
        int i = (bid - 672) * 256 + tid;
        if (i < 512) bqkv[i] = bq[i];
        else if (i < 1024) bqkv[i] = bk[i - 512];
        else if (i < 1536) bqkv[i] = bv[i - 1024];
    }
}

// fused: per-column stats of x [16384,512] + bf16 cast. block = 64 rows.
__global__ __launch_bounds__(256) void k_statcast_x(const float* __restrict__ x,
                                                    short* __restrict__ xb,
                                                    float* __restrict__ psum, float* __restrict__ psq) {
    int b = blockIdx.x, tid = threadIdx.x;
    const float* xp = x + (long)b * 64 * 512;
    short* xo = xb + (long)b * 64 * 512;
    float s0 = 0, q0 = 0, s1 = 0, q1 = 0;
    for (int r = 0; r < 64; ++r) {
        float v0 = xp[r * 512 + tid];
        float v1 = xp[r * 512 + tid + 256];
        xo[r * 512 + tid] = f2b(v0);
        xo[r * 512 + tid + 256] = f2b(v1);
        s0 += v0; q0 += v0 * v0; s1 += v1; q1 += v1 * v1;
    }
    psum[b * 512 + tid] = s0; psum[b * 512 + tid + 256] = s1;
    psq[b * 512 + tid] = q0;  psq[b * 512 + tid + 256] = q1;
}

// ---- parallel finalize: grid = ncols/64, block = 4 part-groups x 64 cols ----

__global__ __launch_bounds__(256) void k_finalize_meanrs(const float* __restrict__ psum,
                                                         const float* __restrict__ psq,
                                                         int nparts, int ncols, float invB,
                                                         float* __restrict__ mean, float* __restrict__ rs) {
    int l = threadIdx.x & 63, grp = threadIdx.x >> 6;
    int c = blockIdx.x * 64 + l;
    float s = 0, q = 0;
    for (int p = grp; p < nparts; p += 4) {
        s += psum[(long)p * ncols + c];
        q += psq[(long)p * ncols + c];
    }
    __shared__ float rs_[4][64], rq_[4][64];
    rs_[grp][l] = s; rq_[grp][l] = q;
    __syncthreads();
    if (grp == 0) {
        s = rs_[0][l] + rs_[1][l] + rs_[2][l] + rs_[3][l];
        q = rq_[0][l] + rq_[1][l] + rq_[2][l] + rq_[3][l];
        float m = s * invB;
        float v = q * invB - m * m;
        mean[c] = m;
        rs[c] = rsqrtf(v + EPS);
    }
}

__global__ __launch_bounds__(256) void k_finalize_ss(const float* __restrict__ psum,
                                                     const float* __restrict__ psq,
                                                     int nparts, int ncols, float invB,
                                                     const float* __restrict__ g, const float* __restrict__ bb,
                                                     float* __restrict__ scale, float* __restrict__ shift) {
    int l = threadIdx.x & 63, grp = threadIdx.x >> 6;
    int c = blockIdx.x * 64 + l;
    float s = 0, q = 0;
    for (int p = grp; p < nparts; p += 4) {
        s += psum[(long)p * ncols + c];
        q += psq[(long)p * ncols + c];
    }
    __shared__ float rs_[4][64], rq_[4][64];
    rs_[grp][l] = s; rq_[grp][l] = q;
    __syncthreads();
    if (grp == 0) {
        s = rs_[0][l] + rs_[1][l] + rs_[2][l] + rs_[3][l];
        q = rq_[0][l] + rq_[1][l] + rq_[2][l] + rq_[3][l];
        float m = s * invB, v = q * invB - m * m;
        float sc = g[c] * rsqrtf(v + EPS);
        scale[c] = sc;
        shift[c] = bb[c] - m * sc;
    }
}

// fold BN1 into w1: block = one (d,o) row
__global__ __launch_bounds__(256) void k_fold_w1(const float* __restrict__ w1, const float* __restrict__ g1,
                                                 const float* __restrict__ b1, const float* __restrict__ mean,
                                                 const float* __restrict__ rs,
                                                 short* __restrict__ W1b, float* __restrict__ beff) {
    int bx = blockIdx.x;  // d*512 + o
    int d = bx >> 9, tid = threadIdx.x;
    const float* wrow = w1 + (long)bx * 512;
    float part = 0.f;
    for (int i = tid; i < 512; i += 256) {
        float wv = wrow[i];
        float sc = rs[i] * g1[d * 512 + i];
        W1b[(long)bx * 512 + i] = f2b(wv * sc);
        part += (b1[d * 512 + i] - mean[i] * sc) * wv;
    }
    __shared__ float red[256];
    red[tid] = part;
    __syncthreads();
    for (int st = 128; st > 0; st >>= 1) {
        if (tid < st) red[tid] += red[tid + st];
        __syncthreads();
    }
    if (tid == 0) beff[bx] = red[0];
}

// t = sigmoid(h*scale + shift), bf16, in-place safe (elementwise same-index)
__global__ __launch_bounds__(256) void k_bnsig(const short* h, short* t,
                                               const float* __restrict__ scale,
                                               const float* __restrict__ shift) {
    long i8 = ((long)blockIdx.x * 256 + threadIdx.x) * 8;
    int c0 = (int)(i8 & 2047);
    bf16x8 v = *(const bf16x8*)(h + i8);
    bf16x8 o;
#pragma unroll
    for (int j = 0; j < 8; ++j) {
        float x = b2f(v[j]) * scale[c0 + j] + shift[c0 + j];
        o[j] = f2b(1.f / (1.f + __expf(-x)));
    }
    *(bf16x8*)(t + i8) = o;
}

// LayerNorm over last dim 512, one wave per token; in-place safe
__global__ __launch_bounds__(256) void k_ln(const short* in, short* out,
                                            const float* __restrict__ g, const float* __restrict__ bb) {
    int w = threadIdx.x >> 6, lane = threadIdx.x & 63;
    long row = (long)blockIdx.x * 4 + w;
    const short* rp = in + row * 512;
    bf16x8 v = *(const bf16x8*)(rp + lane * 8);
    float f[8];
    float s = 0.f;
#pragma unroll
    for (int j = 0; j < 8; ++j) { f[j] = b2f(v[j]); s += f[j]; }
#pragma unroll
    for (int m = 1; m < 64; m <<= 1) s += __shfl_xor(s, m, 64);
    float mean = s * (1.f / 512.f);
    float q = 0.f;
#pragma unroll
    for (int j = 0; j < 8; ++j) { float d = f[j] - mean; q += d * d; }
#pragma unroll
    for (int m = 1; m < 64; m <<= 1) q += __shfl_xor(q, m, 64);
    float rs = rsqrtf(q * (1.f / 512.f) + EPS);
    bf16x8 o;
#pragma unroll
    for (int j = 0; j < 8; ++j) {
        int c = lane * 8 + j;
        o[j] = f2b((f[j] - mean) * rs * g[c] + bb[c]);
    }
    *(bf16x8*)(out + row * 512 + lane * 8) = o;
}

// per-feature stats of out_pre [16384,128] f32
__global__ __launch_bounds__(256) void k_stats_o(const float* __restrict__ pre,
                                                 float* __restrict__ psum, float* __restrict__ psq) {
    int b = blockIdx.x, tid = threadIdx.x;
    int c = tid & 127, rh = tid >> 7;
    const float* pp = pre + (long)b * 128 * 128;
    float s = 0, q = 0;
    for (int r = rh; r < 128; r += 2) {
        float v = pp[r * 128 + c];
        s += v; q += v * v;
    }
    psum[(b * 2 + rh) * 128 + c] = s;
    psq[(b * 2 + rh) * 128 + c] = q;
}

__global__ __launch_bounds__(256) void k_bn3sig(const float* __restrict__ pre, float* __restrict__ out,
                                                const float* __restrict__ scale, const float* __restrict__ shift) {
    long i4 = ((long)blockIdx.x * 256 + threadIdx.x) * 4;
    float4v v = *(const float4v*)(pre + i4);
    int c0 = (int)(i4 & 127);
    float4v o;
#pragma unroll
    for (int j = 0; j < 4; ++j) {
        float x = v[j] * scale[c0 + j] + shift[c0 + j];
        o[j] = 1.f / (1.f + __expf(-x));
    }
    *(float4v*)(out + i4) = o;
}

// ---------------- MFMA GEMM: C = A @ W^T (+bias)(+residual) ----------------
// global_load_lds width=16 staging. GRID: blockIdx.x = N-tile (FAST dim),
// blockIdx.y = M-tile — consecutive blocks share one A-panel so A is read
// from HBM once (N-passes re-read only the small weight B, L2-resident).
// C/R deliberately NOT __restrict__ — O-proj writes C in-place over R.

template <int BM, int BN, int WGM, int WGN, bool ADD_RES, bool OUT_BF16>
__global__ __launch_bounds__(WGM* WGN * 64) void k_gemm_bt(
    const short* __restrict__ A, int a_zoff, int lda,
    const short* __restrict__ W, int w_zoff,
    const float* __restrict__ bias, int bias_zoff,
    short* Cb, float* Cf, int c_zoff, int ldc,
    const short* R, int ldr, int K) {
    constexpr int BK = 32;
    constexpr int WM = BM / WGM, WN = BN / WGN;
    constexpr int AM = WM / 16, AN = WN / 16;
    constexpr int NT = WGM * WGN * 64;
    constexpr int CH = (BM + BN) * (BK / 8);

    __shared__ alignas(16) short Smem[(BM + BN) * BK];

    int tid = threadIdx.x;
    int wave = tid >> 6, lane = tid & 63;
    int wm = (wave % WGM) * WM, wn = (wave / WGM) * WN;
    long m0 = (long)blockIdx.y * BM;   // M-tile = slow dim
    int n0 = blockIdx.x * BN;          // N-tile = fast dim (A-panel reuse)
    int z = blockIdx.z;
    const short* Az = A + (long)z * a_zoff;
    const short* Wz = W + (long)z * w_zoff;

    f32x4 acc[AM][AN];
#pragma unroll
    for (int i = 0; i < AM; ++i)
#pragma unroll
        for (int j = 0; j < AN; ++j)
#pragma unroll
            for (int q = 0; q < 4; ++q) acc[i][j][q] = 0.f;

    int fr = lane & 15, ko = (lane >> 4) * 8;

    for (int k0 = 0; k0 < K; k0 += BK) {
#pragma unroll
        for (int c = tid; c < CH; c += NT) {
            int row = c >> 2, koff = (c & 3) * 8;
            const short* g = (row < BM) ? (Az + (m0 + row) * lda + k0 + koff)
                                        : (Wz + (long)(n0 + row - BM) * K + k0 + koff);
            load_lds16(g, (char*)Smem + (size_t)c * 16);
        }
        __syncthreads();
        bf16x8 af[AM], bfr[AN];
#pragma unroll
        for (int i = 0; i < AM; ++i) af[i] = *(const bf16x8*)(&Smem[(wm + i * 16 + fr) * BK + ko]);
#pragma unroll
        for (int j = 0; j < AN; ++j) bfr[j] = *(const bf16x8*)(&Smem[(BM + wn + j * 16 + fr) * BK + ko]);
#pragma unroll
        for (int i = 0; i < AM; ++i)
#pragma unroll
            for (int j = 0; j < AN; ++j)
                acc[i][j] = __builtin_amdgcn_mfma_f32_16x16x32_bf16(af[i], bfr[j], acc[i][j], 0, 0, 0);
        __syncthreads();
    }

    int cr = (lane >> 4) * 4, cc = lane & 15;
#pragma unroll
    for (int i = 0; i < AM; ++i) {
#pragma unroll
        for (int j = 0; j < AN; ++j) {
            int col = n0 + wn + j * 16 + cc;
            float bv = bias ? bias[(long)z * bias_zoff + col] : 0.f;
#pragma unroll
            for (int q = 0; q < 4; ++q) {
                long row = m0 + wm + i * 16 + cr + q;
                float v = acc[i][j][q] + bv;
                if constexpr (ADD_RES) v += b2f(R[row * (long)ldr + col]);
                long idx = row * (long)ldc + (long)z * c_zoff + col;
                if constexpr (OUT_BF16) Cb[idx] = f2b(v);
                else Cf[idx] = v;
            }
        }
    }
}

// ---------------- E1 GEMM with fused BN2 column-stats epilogue ----------------
// grid (4 N-tiles [fast], 128 M-tiles, 4 z). Stats part index = M-tile (blockIdx.y).

__global__ __launch_bounds__(256) void k_gemm_e1(
    const short* __restrict__ A, const short* __restrict__ W1, const float* __restrict__ beff,
    short* __restrict__ h, float* __restrict__ psum, float* __restrict__ psq) {
    constexpr int BK = 32;
    __shared__ alignas(16) short Smem[256 * BK];  // 16KB
    __shared__ float cS[2][128], cQ[2][128];

    int tid = threadIdx.x;
    int wave = tid >> 6, lane = tid & 63;
    int wm = (wave & 1) * 64, wn = (wave >> 1) * 64;
    long m0 = (long)blockIdx.y * 128;
    int n0 = blockIdx.x * 128;
    int z = blockIdx.z;
    const short* Wz = W1 + (long)z * 512 * 512;

    f32x4 acc[4][4];
#pragma unroll
    for (int i = 0; i < 4; ++i)
#pragma unroll
        for (int j = 0; j < 4; ++j)
#pragma unroll
            for (int q = 0; q < 4; ++q) acc[i][j][q] = 0.f;

    int fr = lane & 15, ko = (lane >> 4) * 8;

    for (int k0 = 0; k0 < 512; k0 += BK) {
#pragma unroll
        for (int c = tid; c < 1024; c += 256) {
            int row = c >> 2, koff = (c & 3) * 8;
            const short* g = (row < 128) ? (A + (m0 + row) * 512 + k0 + koff)
                                         : (Wz + (long)(n0 + row - 128) * 512 + k0 + koff);
            load_lds16(g, (char*)Smem + (size_t)c * 16);
        }
        __syncthreads();
        bf16x8 af[4], bfr[4];
#pragma unroll
        for (int i = 0; i < 4; ++i) af[i] = *(const bf16x8*)(&Smem[(wm + i * 16 + fr) * BK + ko]);
#pragma unroll
        for (int j = 0; j < 4; ++j) bfr[j] = *(const bf16x8*)(&Smem[(128 + wn + j * 16 + fr) * BK + ko]);
#pragma unroll
        for (int i = 0; i < 4; ++i)
#pragma unroll
            for (int j = 0; j < 4; ++j)
                acc[i][j] = __builtin_amdgcn_mfma_f32_16x16x32_bf16(af[i], bfr[j], acc[i][j], 0, 0, 0);
        __syncthreads();
    }

    int cr = (lane >> 4) * 4, cc = lane & 15;
    float bv[4], colS[4], colQ[4];
#pragma unroll
    for (int j = 0; j < 4; ++j) {
        bv[j] = beff[z * 512 + n0 + wn + j * 16 + cc];
        colS[j] = 0.f; colQ[j] = 0.f;
    }
#pragma unroll
    for (int i = 0; i < 4; ++i)
#pragma unroll
        for (int j = 0; j < 4; ++j)
#pragma unroll
            for (int q = 0; q < 4; ++q) {
                float v = acc[i][j][q] + bv[j];
                acc[i][j][q] = v;
                colS[j] += v; colQ[j] += v * v;
            }
#pragma unroll
    for (int i = 0; i < 4; ++i)
#pragma unroll
        for (int q = 0; q < 4; ++q) {
            long row = m0 + wm + i * 16 + cr + q;
            short* hp = h + row * 2048 + z * 512 + n0 + wn + cc;
#pragma unroll
            for (int j = 0; j < 4; ++j) hp[j * 16] = f2b(acc[i][j][q]);
        }
#pragma unroll
    for (int j = 0; j < 4; ++j) {
        float s = colS[j], qq = colQ[j];
        s += __shfl_xor(s, 16, 64); s += __shfl_xor(s, 32, 64);
        qq += __shfl_xor(qq, 16, 64); qq += __shfl_xor(qq, 32, 64);
        if (lane < 16) { cS[wave & 1][wn + j * 16 + cc] = s; cQ[wave & 1][wn + j * 16 + cc] = qq; }
    }
    __syncthreads();
    if (tid < 128) {
        float S = cS[0][tid] + cS[1][tid];
        float Q = cQ[0][tid] + cQ[1][tid];
        psum[(long)blockIdx.y * 2048 + z * 512 + n0 + tid] = S;
        psq[(long)blockIdx.y * 2048 + z * 512 + n0 + tid] = Q;
    }
}

// ---------------- per-row attention over 4 tokens, 4 heads, hd=128 ----------------
__global__ __launch_bounds__(256) void k_attn(const short* __restrict__ qkv, short* __restrict__ ao) {
    __shared__ alignas(16) short lds[4][4][1544];
    __shared__ float attn_s[4][4][4][4];
    int w = threadIdx.x >> 6, lane = threadIdx.x & 63;
    long n = (long)blockIdx.x * 4 + w;
    const short* src = qkv + n * 4 * 1536;
#pragma unroll
    for (int c = 0; c < 12; ++c) {
        int e = c * 512 + lane * 8;
        *(bf16x8*)(&lds[w][e / 1536][e % 1536]) = *(const bf16x8*)(src + e);
    }
    __syncthreads();
    int h = lane >> 4, a = (lane >> 2) & 3, b = lane & 3;
    const short* qp = &lds[w][a][h * 128];
    const short* kp = &lds[w][b][512 + h * 128];
    float s = 0.f;
#pragma unroll
    for (int j = 0; j < 128; j += 8) {
        bf16x8 qv = *(const bf16x8*)(qp + j);
        bf16x8 kv = *(const bf16x8*)(kp + j);
#pragma unroll
        for (int x = 0; x < 8; ++x) s += b2f(qv[x]) * b2f(kv[x]);
    }
    s *= 0.08838834764831845f;
    float mx = fmaxf(s, __shfl_xor(s, 1, 64));
    mx = fmaxf(mx, __shfl_xor(mx, 2, 64));
    float e = __expf(s - mx);
    float den = e + __shfl_xor(e, 1, 64);
    den += __shfl_xor(den, 2, 64);
    attn_s[w][h][a][b] = e / den;
    __syncthreads();
    int ta = lane >> 4, cg = lane & 15;
#pragma unroll
    for (int hh = 0; hh < 4; ++hh) {
        int c0 = hh * 128 + cg * 8;
        float at0 = attn_s[w][hh][ta][0], at1 = attn_s[w][hh][ta][1];
        float at2 = attn_s[w][hh][ta][2], at3 = attn_s[w][hh][ta][3];
        bf16x8 v0 = *(const bf16x8*)(&lds[w][0][1024 + c0]);
        bf16x8 v1 = *(const bf16x8*)(&lds[w][1][1024 + c0]);
        bf16x8 v2 = *(const bf16x8*)(&lds[w][2][1024 + c0]);
        bf16x8 v3 = *(const bf16x8*)(&lds[w][3][1024 + c0]);
        bf16x8 ov;
#pragma unroll
        for (int j = 0; j < 8; ++j) {
            float val = at0 * b2f(v0[j]) + at1 * b2f(v1[j]) + at2 * b2f(v2[j]) + at3 * b2f(v3[j]);
            ov[j] = f2b(val);
        }
        *(bf16x8*)(ao + (n * 4 + ta) * 512 + c0) = ov;
    }
}

// ---------------- host ----------------

extern "C" void kernel_launch(void* const* d_in, const int* in_sizes, int n_in,
                              void* d_out, int out_size, void* d_ws, size_t ws_size,
                              hipStream_t stream) {
    const float* x = (const float*)d_in[0];
    const float* bn1_g = (const float*)d_in[1];
    const float* bn1_b = (const float*)d_in[2];
    const float* w1 = (const float*)d_in[3];
    const float* bn2_g = (const float*)d_in[4];
    const float* bn2_b = (const float*)d_in[5];
    const float* wq = (const float*)d_in[6];
    const float* bq = (const float*)d_in[7];
    const float* wk = (const float*)d_in[8];
    const float* bk = (const float*)d_in[9];
    const float* wv = (const float*)d_in[10];
    const float* bv = (const float*)d_in[11];
    const float* wo = (const float*)d_in[12];
    const float* bo = (const float*)d_in[13];
    const float* ln1_g = (const float*)d_in[14];
    const float* ln1_b = (const float*)d_in[15];
    const float* wff = (const float*)d_in[16];
    const float* bff = (const float*)d_in[17];
    const float* ln2_g = (const float*)d_in[18];
    const float* ln2_b = (const float*)d_in[19];
    const float* w2 = (const float*)d_in[20];
    const float* bn3_g = (const float*)d_in[21];
    const float* bn3_b = (const float*)d_in[22];
    float* out = (float*)d_out;

    char* ws = (char*)d_ws;
    size_t off = 0;
    auto alloc = [&](size_t bytes) {
        void* p = ws + off;
        off = (off + bytes + 255) & ~(size_t)255;
        return p;
    };

    // ---- fixed allocations (~82 MB) ----
    short* W1b = (short*)alloc(4l * 512 * 512 * 2);
    float* beff = (float*)alloc(4l * 512 * 4);
    short* Wqkvb = (short*)alloc(1536l * 512 * 2);
    float* bqkv = (float*)alloc(1536l * 4);
    short* wo_b = (short*)alloc(512l * 512 * 2);
    short* wff_b = (short*)alloc(512l * 512 * 2);
    short* w2_b = (short*)alloc(4l * 32 * 512 * 2);
    float* mean1 = (float*)alloc(512 * 4);
    float* rs1 = (float*)alloc(512 * 4);
    float* scale2 = (float*)alloc(2048 * 4);
    float* shift2 = (float*)alloc(2048 * 4);
    float* scale3 = (float*)alloc(128 * 4);
    float* shift3 = (float*)alloc(128 * 4);
    float* psum1 = (float*)alloc(256l * 512 * 4);
    float* psq1 = (float*)alloc(256l * 512 * 4);
    float* psum2 = (float*)alloc(128l * 2048 * 4);
    float* psq2 = (float*)alloc(128l * 2048 * 4);
    float* psum3 = (float*)alloc(256l * 128 * 4);
    float* psq3 = (float*)alloc(256l * 128 * 4);
    short* slotA = (short*)alloc(16384l * 2048 * 2);  // h -> t -> a1 (in-place)
    float* out_pre = (float*)alloc(16384l * 128 * 4);
    short* bufB = (short*)alloc(16384l * 2048 * 2);   // xb -> attn_o -> a2 (64 MB)

    // ---- qkv chunk arena: NCq batch-rows (qkv only) ----
    long NCq = 1024;
    for (long cand = 8192; cand >= 1024; cand >>= 1) {
        if (off + (size_t)cand * 12288 + (1u << 20) <= ws_size) { NCq = cand; break; }
    }
    short* qkv_c = (short*)alloc((size_t)NCq * 12288);
    short* xb = bufB;  // 16 MB input cast lives in bufB until E1 consumes it

    dim3 B256(256);

    // prep + x cast/stats
    hipLaunchKernelGGL(k_prep, dim3(678), B256, 0, stream,
                       wq, wk, wv, wo, wff, w2, bq, bk, bv,
                       Wqkvb, wo_b, wff_b, w2_b, bqkv);
    hipLaunchKernelGGL(k_statcast_x, dim3(256), B256, 0, stream, x, xb, psum1, psq1);

    // BN1 finalize + fold into E1 weights
    hipLaunchKernelGGL(k_finalize_meanrs, dim3(8), B256, 0, stream, psum1, psq1, 256, 512,
                       1.f / 16384.f, mean1, rs1);
    hipLaunchKernelGGL(k_fold_w1, dim3(2048), B256, 0, stream, w1, bn1_g, bn1_b, mean1, rs1, W1b, beff);

    // E1 + fused BN2 partial stats (grid: N fast, M slow, z)
    hipLaunchKernelGGL(k_gemm_e1, dim3(4, 128, 4), B256, 0, stream,
                       xb, W1b, beff, slotA, psum2, psq2);

    // BN2 finalize + sigmoid -> t (in-place in slotA)
    hipLaunchKernelGGL(k_finalize_ss, dim3(32), B256, 0, stream, psum2, psq2, 128, 2048,
                       1.f / 16384.f, bn2_g, bn2_b, scale2, shift2);
    hipLaunchKernelGGL(k_bnsig, dim3(16384), B256, 0, stream, slotA, slotA, scale2, shift2);

    // ---- QKV + attention (chunked only for workspace; attn_o -> bufB) ----
    long nch = 16384 / NCq;
    for (long c = 0; c < nch; ++c) {
        long r0 = c * NCq;
        const short* t_c = slotA + r0 * 2048;
        int mtiles = (int)(NCq * 4 / 128);

        hipLaunchKernelGGL((k_gemm_bt<128, 128, 2, 2, false, true>), dim3(12, mtiles, 1), B256, 0, stream,
                           t_c, 0, 512, Wqkvb, 0, bqkv, 0,
                           qkv_c, (float*)nullptr, 0, 1536, (const short*)nullptr, 0, 512);

        hipLaunchKernelGGL(k_attn, dim3((int)(NCq / 4)), B256, 0, stream,
                           qkv_c, bufB + r0 * 2048);
    }

    // ---- full-batch tail (A-panel-reuse grids) ----
    // O-proj + bias + residual t, IN-PLACE over t (slotA) -> a1pre
    hipLaunchKernelGGL((k_gemm_bt<128, 128, 2, 2, true, true>), dim3(4, 512, 1), B256, 0, stream,
                       bufB, 0, 512, wo_b, 0, bo, 0,
                       slotA, (float*)nullptr, 0, 512, slotA, 512, 512);

    // LN1 in-place (slotA = a1)
    hipLaunchKernelGGL(k_ln, dim3(16384), B256, 0, stream, slotA, slotA, ln1_g, ln1_b);

    // FF + bias + residual a1 -> a2pre (bufB; attn data dead)
    hipLaunchKernelGGL((k_gemm_bt<128, 128, 2, 2, true, true>), dim3(4, 512, 1), B256, 0, stream,
                       slotA, 0, 512, wff_b, 0, bff, 0,
                       bufB, (float*)nullptr, 0, 512, slotA, 512, 512);

    // LN2 in-place (bufB = a2)
    hipLaunchKernelGGL(k_ln, dim3(16384), B256, 0, stream, bufB, bufB, ln2_g, ln2_b);

    // E2: per-detector [16384,512] @ [32,512]^T -> out_pre (f32)
    hipLaunchKernelGGL((k_gemm_bt<128, 32, 4, 1, false, false>), dim3(1, 128, 4), B256, 0, stream,
                       bufB, 512, 2048, w2_b, 32 * 512, (const float*)nullptr, 0,
                       (short*)nullptr, out_pre, 32, 128, (const short*)nullptr, 0, 512);

    // BN3 + sigmoid -> out
    hipLaunchKernelGGL(k_stats_o, dim3(128), B256, 0, stream, out_pre, psum3, psq3);
    hipLaunchKernelGGL(k_finalize_ss, dim3(2), B256, 0, stream, psum3, psq3, 256, 128,
                       1.f / 16384.f, bn3_g, bn3_b, scale3, shift3);
    hipLaunchKernelGGL(k_bn3sig, dim3(2048), B256, 0, stream, out_pre, out, scale3, shift3);
}

// Round 11
// 614.281 us; speedup vs baseline: 1.1446x; 1.0519x over previous
//
#include <hip/hip_runtime.h>
#include <hip/hip_bf16.h>

#define EPS 1e-5f

typedef __attribute__((ext_vector_type(8))) short bf16x8;
typedef __attribute__((ext_vector_type(4))) float f32x4;
typedef __attribute__((ext_vector_type(4))) float float4v;

__device__ __forceinline__ float b2f(short u) {
    union { unsigned int i; float f; } x;
    x.i = ((unsigned int)(unsigned short)u) << 16;
    return x.f;
}
__device__ __forceinline__ short f2b(float f) {
    unsigned int x = __builtin_bit_cast(unsigned int, f);
    unsigned int r = (x + 0x7FFFu + ((x >> 16) & 1u)) >> 16;
    return (short)r;
}

__device__ __forceinline__ void load_lds16(const void* g, void* l) {
    __builtin_amdgcn_global_load_lds(
        (const __attribute__((address_space(1))) unsigned int*)g,
        (__attribute__((address_space(3))) unsigned int*)l, 16, 0, 0);
}

// ---------------- fused weight prep: 5 big casts + w2 cast + bias concat -----

__device__ __forceinline__ void cast8(const float* __restrict__ src, short* __restrict__ dst, long idx) {
    const float4v* s = (const float4v*)src;
    float4v a = s[idx * 2], b = s[idx * 2 + 1];
    bf16x8 o;
    o[0] = f2b(a[0]); o[1] = f2b(a[1]); o[2] = f2b(a[2]); o[3] = f2b(a[3]);
    o[4] = f2b(b[0]); o[5] = f2b(b[1]); o[6] = f2b(b[2]); o[7] = f2b(b[3]);
    *(bf16x8*)(dst + idx * 8) = o;
}

__global__ __launch_bounds__(256) void k_prep(
    const float* __restrict__ wq, const float* __restrict__ wk, const float* __restrict__ wv,
    const float* __restrict__ wo, const float* __restrict__ wff, const float* __restrict__ w2,
    const float* __restrict__ bq, const float* __restrict__ bk, const float* __restrict__ bv,
    short* __restrict__ Wqkvb, short* __restrict__ wo_b, short* __restrict__ wff_b,
    short* __restrict__ w2_b, float* __restrict__ bqkv) {
    int bid = blockIdx.x, tid = threadIdx.x;
    if (bid < 640) {
        int seg = bid >> 7;
        long idx = (long)(bid & 127) * 256 + tid;
        const float* src;
        short* dst;
        if (seg == 0) { src = wq; dst = Wqkvb; }
        else if (seg == 1) { src = wk; dst = Wqkvb + 262144; }
        else if (seg == 2) { src = wv; dst = Wqkvb + 524288; }
        else if (seg == 3) { src = wo; dst = wo_b; }
        else { src = wff; dst = wff_b; }
        cast8(src, dst, idx);
    } else if (bid < 672) {
        long idx = (long)(bid - 640) * 256 + tid;
        cast8(w2, w2_b, idx);
    } else {
        int i = (bid - 672) * 256 + tid;
        if (i < 512) bqkv[i] = bq[i];
        else if (i < 1024) bqkv[i] = bk[i - 512];
        else if (i < 1536) bqkv[i] = bv[i - 1024];
    }
}

// fused: per-column stats of x [16384,512] + bf16 cast. block = 64 rows.
__global__ __launch_bounds__(256) void k_statcast_x(const float* __restrict__ x,
                                                    short* __restrict__ xb,
                                                    float* __restrict__ psum, float* __restrict__ psq) {
    int b = blockIdx.x, tid = threadIdx.x;
    const float* xp = x + (long)b * 64 * 512;
    short* xo = xb + (long)b * 64 * 512;
    float s0 = 0, q0 = 0, s1 = 0, q1 = 0;
    for (int r = 0; r < 64; ++r) {
        float v0 = xp[r * 512 + tid];
        float v1 = xp[r * 512 + tid + 256];
        xo[r * 512 + tid] = f2b(v0);
        xo[r * 512 + tid + 256] = f2b(v1);
        s0 += v0; q0 += v0 * v0; s1 += v1; q1 += v1 * v1;
    }
    psum[b * 512 + tid] = s0; psum[b * 512 + tid + 256] = s1;
    psq[b * 512 + tid] = q0;  psq[b * 512 + tid + 256] = q1;
}

// ---- parallel finalize: grid = ncols/64, block = 4 part-groups x 64 cols ----

__global__ __launch_bounds__(256) void k_finalize_meanrs(const float* __restrict__ psum,
                                                         const float* __restrict__ psq,
                                                         int nparts, int ncols, float invB,
                                                         float* __restrict__ mean, float* __restrict__ rs) {
    int l = threadIdx.x & 63, grp = threadIdx.x >> 6;
    int c = blockIdx.x * 64 + l;
    float s = 0, q = 0;
    for (int p = grp; p < nparts; p += 4) {
        s += psum[(long)p * ncols + c];
        q += psq[(long)p * ncols + c];
    }
    __shared__ float rs_[4][64], rq_[4][64];
    rs_[grp][l] = s; rq_[grp][l] = q;
    __syncthreads();
    if (grp == 0) {
        s = rs_[0][l] + rs_[1][l] + rs_[2][l] + rs_[3][l];
        q = rq_[0][l] + rq_[1][l] + rq_[2][l] + rq_[3][l];
        float m = s * invB;
        float v = q * invB - m * m;
        mean[c] = m;
        rs[c] = rsqrtf(v + EPS);
    }
}

__global__ __launch_bounds__(256) void k_finalize_ss(const float* __restrict__ psum,
                                                     const float* __restrict__ psq,
                                                     int nparts, int ncols, float invB,
                                                     const float* __restrict__ g, const float* __restrict__ bb,
                                                     float* __restrict__ scale, float* __restrict__ shift) {
    int l = threadIdx.x & 63, grp = threadIdx.x >> 6;
    int c = blockIdx.x * 64 + l;
    float s = 0, q = 0;
    for (int p = grp; p < nparts; p += 4) {
        s += psum[(long)p * ncols + c];
        q += psq[(long)p * ncols + c];
    }
    __shared__ float rs_[4][64], rq_[4][64];
    rs_[grp][l] = s; rq_[grp][l] = q;
    __syncthreads();
    if (grp == 0) {
        s = rs_[0][l] + rs_[1][l] + rs_[2][l] + rs_[3][l];
        q = rq_[0][l] + rq_[1][l] + rq_[2][l] + rq_[3][l];
        float m = s * invB, v = q * invB - m * m;
        float sc = g[c] * rsqrtf(v + EPS);
        scale[c] = sc;
        shift[c] = bb[c] - m * sc;
    }
}

// fold BN1 into w1: block = one (d,o) row
__global__ __launch_bounds__(256) void k_fold_w1(const float* __restrict__ w1, const float* __restrict__ g1,
                                                 const float* __restrict__ b1, const float* __restrict__ mean,
                                                 const float* __restrict__ rs,
                                                 short* __restrict__ W1b, float* __restrict__ beff) {
    int bx = blockIdx.x;  // d*512 + o
    int d = bx >> 9, tid = threadIdx.x;
    const float* wrow = w1 + (long)bx * 512;
    float part = 0.f;
    for (int i = tid; i < 512; i += 256) {
        float wv = wrow[i];
        float sc = rs[i] * g1[d * 512 + i];
        W1b[(long)bx * 512 + i] = f2b(wv * sc);
        part += (b1[d * 512 + i] - mean[i] * sc) * wv;
    }
    __shared__ float red[256];
    red[tid] = part;
    __syncthreads();
    for (int st = 128; st > 0; st >>= 1) {
        if (tid < st) red[tid] += red[tid + st];
        __syncthreads();
    }
    if (tid == 0) beff[bx] = red[0];
}

// t = sigmoid(h*scale + shift), bf16, in-place safe (elementwise same-index)
__global__ __launch_bounds__(256) void k_bnsig(const short* h, short* t,
                                               const float* __restrict__ scale,
                                               const float* __restrict__ shift) {
    long i8 = ((long)blockIdx.x * 256 + threadIdx.x) * 8;
    int c0 = (int)(i8 & 2047);
    bf16x8 v = *(const bf16x8*)(h + i8);
    bf16x8 o;
#pragma unroll
    for (int j = 0; j < 8; ++j) {
        float x = b2f(v[j]) * scale[c0 + j] + shift[c0 + j];
        o[j] = f2b(1.f / (1.f + __expf(-x)));
    }
    *(bf16x8*)(t + i8) = o;
}

// LayerNorm over last dim 512, one wave per token; in-place safe
__global__ __launch_bounds__(256) void k_ln(const short* in, short* out,
                                            const float* __restrict__ g, const float* __restrict__ bb) {
    int w = threadIdx.x >> 6, lane = threadIdx.x & 63;
    long row = (long)blockIdx.x * 4 + w;
    const short* rp = in + row * 512;
    bf16x8 v = *(const bf16x8*)(rp + lane * 8);
    float f[8];
    float s = 0.f;
#pragma unroll
    for (int j = 0; j < 8; ++j) { f[j] = b2f(v[j]); s += f[j]; }
#pragma unroll
    for (int m = 1; m < 64; m <<= 1) s += __shfl_xor(s, m, 64);
    float mean = s * (1.f / 512.f);
    float q = 0.f;
#pragma unroll
    for (int j = 0; j < 8; ++j) { float d = f[j] - mean; q += d * d; }
#pragma unroll
    for (int m = 1; m < 64; m <<= 1) q += __shfl_xor(q, m, 64);
    float rs = rsqrtf(q * (1.f / 512.f) + EPS);
    bf16x8 o;
#pragma unroll
    for (int j = 0; j < 8; ++j) {
        int c = lane * 8 + j;
        o[j] = f2b((f[j] - mean) * rs * g[c] + bb[c]);
    }
    *(bf16x8*)(out + row * 512 + lane * 8) = o;
}

// per-feature stats of out_pre [16384,128] f32
__global__ __launch_bounds__(256) void k_stats_o(const float* __restrict__ pre,
                                                 float* __restrict__ psum, float* __restrict__ psq) {
    int b = blockIdx.x, tid = threadIdx.x;
    int c = tid & 127, rh = tid >> 7;
    const float* pp = pre + (long)b * 128 * 128;
    float s = 0, q = 0;
    for (int r = rh; r < 128; r += 2) {
        float v = pp[r * 128 + c];
        s += v; q += v * v;
    }
    psum[(b * 2 + rh) * 128 + c] = s;
    psq[(b * 2 + rh) * 128 + c] = q;
}

__global__ __launch_bounds__(256) void k_bn3sig(const float* __restrict__ pre, float* __restrict__ out,
                                                const float* __restrict__ scale, const float* __restrict__ shift) {
    long i4 = ((long)blockIdx.x * 256 + threadIdx.x) * 4;
    float4v v = *(const float4v*)(pre + i4);
    int c0 = (int)(i4 & 127);
    float4v o;
#pragma unroll
    for (int j = 0; j < 4; ++j) {
        float x = v[j] * scale[c0 + j] + shift[c0 + j];
        o[j] = 1.f / (1.f + __expf(-x));
    }
    *(float4v*)(out + i4) = o;
}

// ---------------- MFMA GEMM: C = A @ W^T (+bias)(+residual) ----------------
// global_load_lds width=16 staging. grid: blockIdx.x = M-tile (fast, R8 order).
// DBUF path (when CH%NT==0): 2 LDS buffers + counted vmcnt — next tile's loads
// stay in flight ACROSS raw s_barriers (T4 minimum form), hiding HBM/L3 latency
// per K-step. E2's ragged staging keeps the single-buffer __syncthreads path.
// C/R deliberately NOT __restrict__ — O-proj writes C in-place over R.

template <int BM, int BN, int WGM, int WGN, bool ADD_RES, bool OUT_BF16>
__global__ __launch_bounds__(WGM* WGN * 64) void k_gemm_bt(
    const short* __restrict__ A, int a_zoff, int lda,
    const short* __restrict__ W, int w_zoff,
    const float* __restrict__ bias, int bias_zoff,
    short* Cb, float* Cf, int c_zoff, int ldc,
    const short* R, int ldr, int K) {
    constexpr int BK = 32;
    constexpr int WM = BM / WGM, WN = BN / WGN;
    constexpr int AM = WM / 16, AN = WN / 16;
    constexpr int NT = WGM * WGN * 64;
    constexpr int CH = (BM + BN) * (BK / 8);
    constexpr bool DBUF = (CH % NT == 0) && (CH / NT == 4);

    int tid = threadIdx.x;
    int wave = tid >> 6, lane = tid & 63;
    int wm = (wave % WGM) * WM, wn = (wave / WGM) * WN;
    long m0 = (long)blockIdx.x * BM;
    int n0 = blockIdx.y * BN;
    int z = blockIdx.z;
    const short* Az = A + (long)z * a_zoff;
    const short* Wz = W + (long)z * w_zoff;

    f32x4 acc[AM][AN];
#pragma unroll
    for (int i = 0; i < AM; ++i)
#pragma unroll
        for (int j = 0; j < AN; ++j)
#pragma unroll
            for (int q = 0; q < 4; ++q) acc[i][j][q] = 0.f;

    int fr = lane & 15, ko = (lane >> 4) * 8;
    int cr = (lane >> 4) * 4, cc = lane & 15;

    if constexpr (DBUF) {
        __shared__ alignas(16) short Smem[2][(BM + BN) * BK];
        auto stage = [&](int b, int k0) {
#pragma unroll
            for (int i = 0; i < 4; ++i) {
                int c = tid + i * NT;
                int row = c >> 2, koff = (c & 3) * 8;
                const short* g = (row < BM) ? (Az + (m0 + row) * lda + k0 + koff)
                                            : (Wz + (long)(n0 + row - BM) * K + k0 + koff);
                load_lds16(g, (char*)Smem[b] + (size_t)c * 16);
            }
        };
        stage(0, 0);
        int nk = K / BK;
        for (int kt = 0; kt < nk; ++kt) {
            int b = kt & 1;
            if (kt + 1 < nk) {
                stage(b ^ 1, (kt + 1) * BK);              // 4 loads stay in flight
                asm volatile("s_waitcnt vmcnt(4)" ::: "memory");  // own tile-kt loads landed
            } else {
                asm volatile("s_waitcnt vmcnt(0)" ::: "memory");
            }
            __builtin_amdgcn_s_barrier();                  // all waves: buf b ready
            bf16x8 af[AM], bfr[AN];
#pragma unroll
            for (int i = 0; i < AM; ++i)
                af[i] = *(const bf16x8*)(&Smem[b][(wm + i * 16 + fr) * BK + ko]);
#pragma unroll
            for (int j = 0; j < AN; ++j)
                bfr[j] = *(const bf16x8*)(&Smem[b][(BM + wn + j * 16 + fr) * BK + ko]);
#pragma unroll
            for (int i = 0; i < AM; ++i)
#pragma unroll
                for (int j = 0; j < AN; ++j)
                    acc[i][j] = __builtin_amdgcn_mfma_f32_16x16x32_bf16(af[i], bfr[j], acc[i][j], 0, 0, 0);
            asm volatile("s_waitcnt lgkmcnt(0)" ::: "memory");  // reads done before overwrite
            __builtin_amdgcn_s_barrier();
        }
    } else {
        __shared__ alignas(16) short Smem[(BM + BN) * BK];
        for (int k0 = 0; k0 < K; k0 += BK) {
#pragma unroll
            for (int c = tid; c < CH; c += NT) {
                int row = c >> 2, koff = (c & 3) * 8;
                const short* g = (row < BM) ? (Az + (m0 + row) * lda + k0 + koff)
                                            : (Wz + (long)(n0 + row - BM) * K + k0 + koff);
                load_lds16(g, (char*)Smem + (size_t)c * 16);
            }
            __syncthreads();
            bf16x8 af[AM], bfr[AN];
#pragma unroll
            for (int i = 0; i < AM; ++i) af[i] = *(const bf16x8*)(&Smem[(wm + i * 16 + fr) * BK + ko]);
#pragma unroll
            for (int j = 0; j < AN; ++j) bfr[j] = *(const bf16x8*)(&Smem[(BM + wn + j * 16 + fr) * BK + ko]);
#pragma unroll
            for (int i = 0; i < AM; ++i)
#pragma unroll
                for (int j = 0; j < AN; ++j)
                    acc[i][j] = __builtin_amdgcn_mfma_f32_16x16x32_bf16(af[i], bfr[j], acc[i][j], 0, 0, 0);
            __syncthreads();
        }
    }

#pragma unroll
    for (int i = 0; i < AM; ++i) {
#pragma unroll
        for (int j = 0; j < AN; ++j) {
            int col = n0 + wn + j * 16 + cc;
            float bv = bias ? bias[(long)z * bias_zoff + col] : 0.f;
#pragma unroll
            for (int q = 0; q < 4; ++q) {
                long row = m0 + wm + i * 16 + cr + q;
                float v = acc[i][j][q] + bv;
                if constexpr (ADD_RES) v += b2f(R[row * (long)ldr + col]);
                long idx = row * (long)ldc + (long)z * c_zoff + col;
                if constexpr (OUT_BF16) Cb[idx] = f2b(v);
                else Cf[idx] = v;
            }
        }
    }
}

// ---------------- E1 GEMM with fused BN2 column-stats epilogue (dbuf) ---------

__global__ __launch_bounds__(256) void k_gemm_e1(
    const short* __restrict__ A, const short* __restrict__ W1, const float* __restrict__ beff,
    short* __restrict__ h, float* __restrict__ psum, float* __restrict__ psq) {
    constexpr int BK = 32;
    __shared__ alignas(16) short Smem[2][256 * BK];  // 32KB dbuf
    __shared__ float cS[2][128], cQ[2][128];

    int tid = threadIdx.x;
    int wave = tid >> 6, lane = tid & 63;
    int wm = (wave & 1) * 64, wn = (wave >> 1) * 64;
    long m0 = (long)blockIdx.x * 128;
    int n0 = blockIdx.y * 128;
    int z = blockIdx.z;
    const short* Wz = W1 + (long)z * 512 * 512;

    f32x4 acc[4][4];
#pragma unroll
    for (int i = 0; i < 4; ++i)
#pragma unroll
        for (int j = 0; j < 4; ++j)
#pragma unroll
            for (int q = 0; q < 4; ++q) acc[i][j][q] = 0.f;

    int fr = lane & 15, ko = (lane >> 4) * 8;

    auto stage = [&](int b, int k0) {
#pragma unroll
        for (int i = 0; i < 4; ++i) {
            int c = tid + i * 256;
            int row = c >> 2, koff = (c & 3) * 8;
            const short* g = (row < 128) ? (A + (m0 + row) * 512 + k0 + koff)
                                         : (Wz + (long)(n0 + row - 128) * 512 + k0 + koff);
            load_lds16(g, (char*)Smem[b] + (size_t)c * 16);
        }
    };
    stage(0, 0);
    for (int kt = 0; kt < 16; ++kt) {
        int b = kt & 1;
        if (kt + 1 < 16) {
            stage(b ^ 1, (kt + 1) * BK);
            asm volatile("s_waitcnt vmcnt(4)" ::: "memory");
        } else {
            asm volatile("s_waitcnt vmcnt(0)" ::: "memory");
        }
        __builtin_amdgcn_s_barrier();
        bf16x8 af[4], bfr[4];
#pragma unroll
        for (int i = 0; i < 4; ++i) af[i] = *(const bf16x8*)(&Smem[b][(wm + i * 16 + fr) * BK + ko]);
#pragma unroll
        for (int j = 0; j < 4; ++j) bfr[j] = *(const bf16x8*)(&Smem[b][(128 + wn + j * 16 + fr) * BK + ko]);
#pragma unroll
        for (int i = 0; i < 4; ++i)
#pragma unroll
            for (int j = 0; j < 4; ++j)
                acc[i][j] = __builtin_amdgcn_mfma_f32_16x16x32_bf16(af[i], bfr[j], acc[i][j], 0, 0, 0);
        asm volatile("s_waitcnt lgkmcnt(0)" ::: "memory");
        __builtin_amdgcn_s_barrier();
    }

    int cr = (lane >> 4) * 4, cc = lane & 15;
    float bv[4], colS[4], colQ[4];
#pragma unroll
    for (int j = 0; j < 4; ++j) {
        bv[j] = beff[z * 512 + n0 + wn + j * 16 + cc];
        colS[j] = 0.f; colQ[j] = 0.f;
    }
#pragma unroll
    for (int i = 0; i < 4; ++i)
#pragma unroll
        for (int j = 0; j < 4; ++j)
#pragma unroll
            for (int q = 0; q < 4; ++q) {
                float v = acc[i][j][q] + bv[j];
                acc[i][j][q] = v;
                colS[j] += v; colQ[j] += v * v;
            }
#pragma unroll
    for (int i = 0; i < 4; ++i)
#pragma unroll
        for (int q = 0; q < 4; ++q) {
            long row = m0 + wm + i * 16 + cr + q;
            short* hp = h + row * 2048 + z * 512 + n0 + wn + cc;
#pragma unroll
            for (int j = 0; j < 4; ++j) hp[j * 16] = f2b(acc[i][j][q]);
        }
#pragma unroll
    for (int j = 0; j < 4; ++j) {
        float s = colS[j], qq = colQ[j];
        s += __shfl_xor(s, 16, 64); s += __shfl_xor(s, 32, 64);
        qq += __shfl_xor(qq, 16, 64); qq += __shfl_xor(qq, 32, 64);
        if (lane < 16) { cS[wave & 1][wn + j * 16 + cc] = s; cQ[wave & 1][wn + j * 16 + cc] = qq; }
    }
    __syncthreads();
    if (tid < 128) {
        float S = cS[0][tid] + cS[1][tid];
        float Q = cQ[0][tid] + cQ[1][tid];
        psum[(long)blockIdx.x * 2048 + z * 512 + n0 + tid] = S;
        psq[(long)blockIdx.x * 2048 + z * 512 + n0 + tid] = Q;
    }
}

// ---------------- per-row attention over 4 tokens, 4 heads, hd=128 ----------------
__global__ __launch_bounds__(256) void k_attn(const short* __restrict__ qkv, short* __restrict__ ao) {
    __shared__ alignas(16) short lds[4][4][1544];
    __shared__ float attn_s[4][4][4][4];
    int w = threadIdx.x >> 6, lane = threadIdx.x & 63;
    long n = (long)blockIdx.x * 4 + w;
    const short* src = qkv + n * 4 * 1536;
#pragma unroll
    for (int c = 0; c < 12; ++c) {
        int e = c * 512 + lane * 8;
        *(bf16x8*)(&lds[w][e / 1536][e % 1536]) = *(const bf16x8*)(src + e);
    }
    __syncthreads();
    int h = lane >> 4, a = (lane >> 2) & 3, b = lane & 3;
    const short* qp = &lds[w][a][h * 128];
    const short* kp = &lds[w][b][512 + h * 128];
    float s = 0.f;
#pragma unroll
    for (int j = 0; j < 128; j += 8) {
        bf16x8 qv = *(const bf16x8*)(qp + j);
        bf16x8 kv = *(const bf16x8*)(kp + j);
#pragma unroll
        for (int x = 0; x < 8; ++x) s += b2f(qv[x]) * b2f(kv[x]);
    }
    s *= 0.08838834764831845f;
    float mx = fmaxf(s, __shfl_xor(s, 1, 64));
    mx = fmaxf(mx, __shfl_xor(mx, 2, 64));
    float e = __expf(s - mx);
    float den = e + __shfl_xor(e, 1, 64);
    den += __shfl_xor(den, 2, 64);
    attn_s[w][h][a][b] = e / den;
    __syncthreads();
    int ta = lane >> 4, cg = lane & 15;
#pragma unroll
    for (int hh = 0; hh < 4; ++hh) {
        int c0 = hh * 128 + cg * 8;
        float at0 = attn_s[w][hh][ta][0], at1 = attn_s[w][hh][ta][1];
        float at2 = attn_s[w][hh][ta][2], at3 = attn_s[w][hh][ta][3];
        bf16x8 v0 = *(const bf16x8*)(&lds[w][0][1024 + c0]);
        bf16x8 v1 = *(const bf16x8*)(&lds[w][1][1024 + c0]);
        bf16x8 v2 = *(const bf16x8*)(&lds[w][2][1024 + c0]);
        bf16x8 v3 = *(const bf16x8*)(&lds[w][3][1024 + c0]);
        bf16x8 ov;
#pragma unroll
        for (int j = 0; j < 8; ++j) {
            float val = at0 * b2f(v0[j]) + at1 * b2f(v1[j]) + at2 * b2f(v2[j]) + at3 * b2f(v3[j]);
            ov[j] = f2b(val);
        }
        *(bf16x8*)(ao + (n * 4 + ta) * 512 + c0) = ov;
    }
}

// ---------------- host ----------------

extern "C" void kernel_launch(void* const* d_in, const int* in_sizes, int n_in,
                              void* d_out, int out_size, void* d_ws, size_t ws_size,
                              hipStream_t stream) {
    const float* x = (const float*)d_in[0];
    const float* bn1_g = (const float*)d_in[1];
    const float* bn1_b = (const float*)d_in[2];
    const float* w1 = (const float*)d_in[3];
    const float* bn2_g = (const float*)d_in[4];
    const float* bn2_b = (const float*)d_in[5];
    const float* wq = (const float*)d_in[6];
    const float* bq = (const float*)d_in[7];
    const float* wk = (const float*)d_in[8];
    const float* bk = (const float*)d_in[9];
    const float* wv = (const float*)d_in[10];
    const float* bv = (const float*)d_in[11];
    const float* wo = (const float*)d_in[12];
    const float* bo = (const float*)d_in[13];
    const float* ln1_g = (const float*)d_in[14];
    const float* ln1_b = (const float*)d_in[15];
    const float* wff = (const float*)d_in[16];
    const float* bff = (const float*)d_in[17];
    const float* ln2_g = (const float*)d_in[18];
    const float* ln2_b = (const float*)d_in[19];
    const float* w2 = (const float*)d_in[20];
    const float* bn3_g = (const float*)d_in[21];
    const float* bn3_b = (const float*)d_in[22];
    float* out = (float*)d_out;

    char* ws = (char*)d_ws;
    size_t off = 0;
    auto alloc = [&](size_t bytes) {
        void* p = ws + off;
        off = (off + bytes + 255) & ~(size_t)255;
        return p;
    };

    // ---- fixed allocations (~82 MB) ----
    short* W1b = (short*)alloc(4l * 512 * 512 * 2);
    float* beff = (float*)alloc(4l * 512 * 4);
    short* Wqkvb = (short*)alloc(1536l * 512 * 2);
    float* bqkv = (float*)alloc(1536l * 4);
    short* wo_b = (short*)alloc(512l * 512 * 2);
    short* wff_b = (short*)alloc(512l * 512 * 2);
    short* w2_b = (short*)alloc(4l * 32 * 512 * 2);
    float* mean1 = (float*)alloc(512 * 4);
    float* rs1 = (float*)alloc(512 * 4);
    float* scale2 = (float*)alloc(2048 * 4);
    float* shift2 = (float*)alloc(2048 * 4);
    float* scale3 = (float*)alloc(128 * 4);
    float* shift3 = (float*)alloc(128 * 4);
    float* psum1 = (float*)alloc(256l * 512 * 4);
    float* psq1 = (float*)alloc(256l * 512 * 4);
    float* psum2 = (float*)alloc(128l * 2048 * 4);
    float* psq2 = (float*)alloc(128l * 2048 * 4);
    float* psum3 = (float*)alloc(256l * 128 * 4);
    float* psq3 = (float*)alloc(256l * 128 * 4);
    short* slotA = (short*)alloc(16384l * 2048 * 2);  // h -> t -> a1 (in-place)
    float* out_pre = (float*)alloc(16384l * 128 * 4);
    short* bufB = (short*)alloc(16384l * 2048 * 2);   // xb -> attn_o -> a2 (64 MB)

    // ---- qkv chunk arena: NCq batch-rows (qkv only) ----
    long NCq = 1024;
    for (long cand = 4096; cand >= 1024; cand >>= 1) {
        if (off + (size_t)cand * 12288 + (1u << 20) <= ws_size) { NCq = cand; break; }
    }
    short* qkv_c = (short*)alloc((size_t)NCq * 12288);
    short* xb = bufB;  // 16 MB input cast lives in bufB until E1 consumes it

    dim3 B256(256);

    // prep + x cast/stats
    hipLaunchKernelGGL(k_prep, dim3(678), B256, 0, stream,
                       wq, wk, wv, wo, wff, w2, bq, bk, bv,
                       Wqkvb, wo_b, wff_b, w2_b, bqkv);
    hipLaunchKernelGGL(k_statcast_x, dim3(256), B256, 0, stream, x, xb, psum1, psq1);

    // BN1 finalize + fold into E1 weights
    hipLaunchKernelGGL(k_finalize_meanrs, dim3(8), B256, 0, stream, psum1, psq1, 256, 512,
                       1.f / 16384.f, mean1, rs1);
    hipLaunchKernelGGL(k_fold_w1, dim3(2048), B256, 0, stream, w1, bn1_g, bn1_b, mean1, rs1, W1b, beff);

    // E1 + fused BN2 partial stats (xb in bufB; h -> slotA)
    hipLaunchKernelGGL(k_gemm_e1, dim3(128, 4, 4), B256, 0, stream,
                       xb, W1b, beff, slotA, psum2, psq2);

    // BN2 finalize + sigmoid -> t (in-place in slotA)
    hipLaunchKernelGGL(k_finalize_ss, dim3(32), B256, 0, stream, psum2, psq2, 128, 2048,
                       1.f / 16384.f, bn2_g, bn2_b, scale2, shift2);
    hipLaunchKernelGGL(k_bnsig, dim3(16384), B256, 0, stream, slotA, slotA, scale2, shift2);

    // ---- QKV + attention (chunked for workspace; attn_o -> bufB) ----
    long nch = 16384 / NCq;
    for (long c = 0; c < nch; ++c) {
        long r0 = c * NCq;
        const short* t_c = slotA + r0 * 2048;
        int gx = (int)(NCq * 4 / 128);

        hipLaunchKernelGGL((k_gemm_bt<128, 128, 2, 2, false, true>), dim3(gx, 12, 1), B256, 0, stream,
                           t_c, 0, 512, Wqkvb, 0, bqkv, 0,
                           qkv_c, (float*)nullptr, 0, 1536, (const short*)nullptr, 0, 512);

        hipLaunchKernelGGL(k_attn, dim3((int)(NCq / 4)), B256, 0, stream,
                           qkv_c, bufB + r0 * 2048);
    }

    // ---- full-batch tail ----
    // O-proj + bias + residual t, IN-PLACE over t (slotA) -> a1pre
    hipLaunchKernelGGL((k_gemm_bt<128, 128, 2, 2, true, true>), dim3(512, 4, 1), B256, 0, stream,
                       bufB, 0, 512, wo_b, 0, bo, 0,
                       slotA, (float*)nullptr, 0, 512, slotA, 512, 512);

    // LN1 in-place (slotA = a1)
    hipLaunchKernelGGL(k_ln, dim3(16384), B256, 0, stream, slotA, slotA, ln1_g, ln1_b);

    // FF + bias + residual a1 -> a2pre (bufB; attn data dead)
    hipLaunchKernelGGL((k_gemm_bt<128, 128, 2, 2, true, true>), dim3(512, 4, 1), B256, 0, stream,
                       slotA, 0, 512, wff_b, 0, bff, 0,
                       bufB, (float*)nullptr, 0, 512, slotA, 512, 512);

    // LN2 in-place (bufB = a2)
    hipLaunchKernelGGL(k_ln, dim3(16384), B256, 0, stream, bufB, bufB, ln2_g, ln2_b);

    // E2: per-detector [16384,512] @ [32,512]^T -> out_pre (f32)
    hipLaunchKernelGGL((k_gemm_bt<128, 32, 4, 1, false, false>), dim3(128, 1, 4), B256, 0, stream,
                       bufB, 512, 2048, w2_b, 32 * 512, (const float*)nullptr, 0,
                       (short*)nullptr, out_pre, 32, 128, (const short*)nullptr, 0, 512);

    // BN3 + sigmoid -> out
    hipLaunchKernelGGL(k_stats_o, dim3(128), B256, 0, stream, out_pre, psum3, psq3);
    hipLaunchKernelGGL(k_finalize_ss, dim3(2), B256, 0, stream, psum3, psq3, 256, 128,
                       1.f / 16384.f, bn3_g, bn3_b, scale3, shift3);
    hipLaunchKernelGGL(k_bn3sig, dim3(2048), B256, 0, stream, out_pre, out, scale3, shift3);
}

// Round 12
// 575.163 us; speedup vs baseline: 1.2224x; 1.0680x over previous
//
#include <hip/hip_runtime.h>
#include <hip/hip_bf16.h>

#define EPS 1e-5f

typedef __attribute__((ext_vector_type(8))) short bf16x8;
typedef __attribute__((ext_vector_type(4))) float f32x4;
typedef __attribute__((ext_vector_type(4))) float float4v;

__device__ __forceinline__ float b2f(short u) {
    union { unsigned int i; float f; } x;
    x.i = ((unsigned int)(unsigned short)u) << 16;
    return x.f;
}
__device__ __forceinline__ short f2b(float f) {
    unsigned int x = __builtin_bit_cast(unsigned int, f);
    unsigned int r = (x + 0x7FFFu + ((x >> 16) & 1u)) >> 16;
    return (short)r;
}

__device__ __forceinline__ void load_lds16(const void* g, void* l) {
    __builtin_amdgcn_global_load_lds(
        (const __attribute__((address_space(1))) unsigned int*)g,
        (__attribute__((address_space(3))) unsigned int*)l, 16, 0, 0);
}

// ---------------- fused weight prep: 5 big casts + w2 cast + bias concat -----

__device__ __forceinline__ void cast8(const float* __restrict__ src, short* __restrict__ dst, long idx) {
    const float4v* s = (const float4v*)src;
    float4v a = s[idx * 2], b = s[idx * 2 + 1];
    bf16x8 o;
    o[0] = f2b(a[0]); o[1] = f2b(a[1]); o[2] = f2b(a[2]); o[3] = f2b(a[3]);
    o[4] = f2b(b[0]); o[5] = f2b(b[1]); o[6] = f2b(b[2]); o[7] = f2b(b[3]);
    *(bf16x8*)(dst + idx * 8) = o;
}

__global__ __launch_bounds__(256) void k_prep(
    const float* __restrict__ wq, const float* __restrict__ wk, const float* __restrict__ wv,
    const float* __restrict__ wo, const float* __restrict__ wff, const float* __restrict__ w2,
    const float* __restrict__ bq, const float* __restrict__ bk, const float* __restrict__ bv,
    short* __restrict__ Wqkvb, short* __restrict__ wo_b, short* __restrict__ wff_b,
    short* __restrict__ w2_b, float* __restrict__ bqkv) {
    int bid = blockIdx.x, tid = threadIdx.x;
    if (bid < 640) {
        int seg = bid >> 7;
        long idx = (long)(bid & 127) * 256 + tid;
        const float* src;
        short* dst;
        if (seg == 0) { src = wq; dst = Wqkvb; }
        else if (seg == 1) { src = wk; dst = Wqkvb + 262144; }
        else if (seg == 2) { src = wv; dst = Wqkvb + 524288; }
        else if (seg == 3) { src = wo; dst = wo_b; }
        else { src = wff; dst = wff_b; }
        cast8(src, dst, idx);
    } else if (bid < 672) {
        long idx = (long)(bid - 640) * 256 + tid;
        cast8(w2, w2_b, idx);
    } else {
        int i = (bid - 672) * 256 + tid;
        if (i < 512) bqkv[i] = bq[i];
        else if (i < 1024) bqkv[i] = bk[i - 512];
        else if (i < 1536) bqkv[i] = bv[i - 1024];
    }
}

// fused: per-column stats of x [16384,512] + bf16 cast. block = 64 rows.
__global__ __launch_bounds__(256) void k_statcast_x(const float* __restrict__ x,
                                                    short* __restrict__ xb,
                                                    float* __restrict__ psum, float* __restrict__ psq) {
    int b = blockIdx.x, tid = threadIdx.x;
    const float* xp = x + (long)b * 64 * 512;
    short* xo = xb + (long)b * 64 * 512;
    float s0 = 0, q0 = 0, s1 = 0, q1 = 0;
    for (int r = 0; r < 64; ++r) {
        float v0 = xp[r * 512 + tid];
        float v1 = xp[r * 512 + tid + 256];
        xo[r * 512 + tid] = f2b(v0);
        xo[r * 512 + tid + 256] = f2b(v1);
        s0 += v0; q0 += v0 * v0; s1 += v1; q1 += v1 * v1;
    }
    psum[b * 512 + tid] = s0; psum[b * 512 + tid + 256] = s1;
    psq[b * 512 + tid] = q0;  psq[b * 512 + tid + 256] = q1;
}

// ---- parallel finalize: grid = ncols/64, block = 4 part-groups x 64 cols ----

__global__ __launch_bounds__(256) void k_finalize_meanrs(const float* __restrict__ psum,
                                                         const float* __restrict__ psq,
                                                         int nparts, int ncols, float invB,
                                                         float* __restrict__ mean, float* __restrict__ rs) {
    int l = threadIdx.x & 63, grp = threadIdx.x >> 6;
    int c = blockIdx.x * 64 + l;
    float s = 0, q = 0;
    for (int p = grp; p < nparts; p += 4) {
        s += psum[(long)p * ncols + c];
        q += psq[(long)p * ncols + c];
    }
    __shared__ float rs_[4][64], rq_[4][64];
    rs_[grp][l] = s; rq_[grp][l] = q;
    __syncthreads();
    if (grp == 0) {
        s = rs_[0][l] + rs_[1][l] + rs_[2][l] + rs_[3][l];
        q = rq_[0][l] + rq_[1][l] + rq_[2][l] + rq_[3][l];
        float m = s * invB;
        float v = q * invB - m * m;
        mean[c] = m;
        rs[c] = rsqrtf(v + EPS);
    }
}

__global__ __launch_bounds__(256) void k_finalize_ss(const float* __restrict__ psum,
                                                     const float* __restrict__ psq,
                                                     int nparts, int ncols, float invB,
                                                     const float* __restrict__ g, const float* __restrict__ bb,
                                                     float* __restrict__ scale, float* __restrict__ shift) {
    int l = threadIdx.x & 63, grp = threadIdx.x >> 6;
    int c = blockIdx.x * 64 + l;
    float s = 0, q = 0;
    for (int p = grp; p < nparts; p += 4) {
        s += psum[(long)p * ncols + c];
        q += psq[(long)p * ncols + c];
    }
    __shared__ float rs_[4][64], rq_[4][64];
    rs_[grp][l] = s; rq_[grp][l] = q;
    __syncthreads();
    if (grp == 0) {
        s = rs_[0][l] + rs_[1][l] + rs_[2][l] + rs_[3][l];
        q = rq_[0][l] + rq_[1][l] + rq_[2][l] + rq_[3][l];
        float m = s * invB, v = q * invB - m * m;
        float sc = g[c] * rsqrtf(v + EPS);
        scale[c] = sc;
        shift[c] = bb[c] - m * sc;
    }
}

// fold BN1 into w1: block = one (d,o) row
__global__ __launch_bounds__(256) void k_fold_w1(const float* __restrict__ w1, const float* __restrict__ g1,
                                                 const float* __restrict__ b1, const float* __restrict__ mean,
                                                 const float* __restrict__ rs,
                                                 short* __restrict__ W1b, float* __restrict__ beff) {
    int bx = blockIdx.x;  // d*512 + o
    int d = bx >> 9, tid = threadIdx.x;
    const float* wrow = w1 + (long)bx * 512;
    float part = 0.f;
    for (int i = tid; i < 512; i += 256) {
        float wv = wrow[i];
        float sc = rs[i] * g1[d * 512 + i];
        W1b[(long)bx * 512 + i] = f2b(wv * sc);
        part += (b1[d * 512 + i] - mean[i] * sc) * wv;
    }
    __shared__ float red[256];
    red[tid] = part;
    __syncthreads();
    for (int st = 128; st > 0; st >>= 1) {
        if (tid < st) red[tid] += red[tid + st];
        __syncthreads();
    }
    if (tid == 0) beff[bx] = red[0];
}

// t = sigmoid(h*scale + shift), bf16, in-place safe (elementwise same-index)
__global__ __launch_bounds__(256) void k_bnsig(const short* h, short* t,
                                               const float* __restrict__ scale,
                                               const float* __restrict__ shift) {
    long i8 = ((long)blockIdx.x * 256 + threadIdx.x) * 8;
    int c0 = (int)(i8 & 2047);
    bf16x8 v = *(const bf16x8*)(h + i8);
    bf16x8 o;
#pragma unroll
    for (int j = 0; j < 8; ++j) {
        float x = b2f(v[j]) * scale[c0 + j] + shift[c0 + j];
        o[j] = f2b(1.f / (1.f + __expf(-x)));
    }
    *(bf16x8*)(t + i8) = o;
}

// LayerNorm over last dim 512, one wave per token; in-place safe
__global__ __launch_bounds__(256) void k_ln(const short* in, short* out,
                                            const float* __restrict__ g, const float* __restrict__ bb) {
    int w = threadIdx.x >> 6, lane = threadIdx.x & 63;
    long row = (long)blockIdx.x * 4 + w;
    const short* rp = in + row * 512;
    bf16x8 v = *(const bf16x8*)(rp + lane * 8);
    float f[8];
    float s = 0.f;
#pragma unroll
    for (int j = 0; j < 8; ++j) { f[j] = b2f(v[j]); s += f[j]; }
#pragma unroll
    for (int m = 1; m < 64; m <<= 1) s += __shfl_xor(s, m, 64);
    float mean = s * (1.f / 512.f);
    float q = 0.f;
#pragma unroll
    for (int j = 0; j < 8; ++j) { float d = f[j] - mean; q += d * d; }
#pragma unroll
    for (int m = 1; m < 64; m <<= 1) q += __shfl_xor(q, m, 64);
    float rs = rsqrtf(q * (1.f / 512.f) + EPS);
    bf16x8 o;
#pragma unroll
    for (int j = 0; j < 8; ++j) {
        int c = lane * 8 + j;
        o[j] = f2b((f[j] - mean) * rs * g[c] + bb[c]);
    }
    *(bf16x8*)(out + row * 512 + lane * 8) = o;
}

// per-feature stats of out_pre [16384,128] f32
__global__ __launch_bounds__(256) void k_stats_o(const float* __restrict__ pre,
                                                 float* __restrict__ psum, float* __restrict__ psq) {
    int b = blockIdx.x, tid = threadIdx.x;
    int c = tid & 127, rh = tid >> 7;
    const float* pp = pre + (long)b * 128 * 128;
    float s = 0, q = 0;
    for (int r = rh; r < 128; r += 2) {
        float v = pp[r * 128 + c];
        s += v; q += v * v;
    }
    psum[(b * 2 + rh) * 128 + c] = s;
    psq[(b * 2 + rh) * 128 + c] = q;
}

__global__ __launch_bounds__(256) void k_bn3sig(const float* __restrict__ pre, float* __restrict__ out,
                                                const float* __restrict__ scale, const float* __restrict__ shift) {
    long i4 = ((long)blockIdx.x * 256 + threadIdx.x) * 4;
    float4v v = *(const float4v*)(pre + i4);
    int c0 = (int)(i4 & 127);
    float4v o;
#pragma unroll
    for (int j = 0; j < 4; ++j) {
        float x = v[j] * scale[c0 + j] + shift[c0 + j];
        o[j] = 1.f / (1.f + __expf(-x));
    }
    *(float4v*)(out + i4) = o;
}

// ---------------- MFMA GEMM: C = A @ W^T (+bias)(+residual) ----------------
// global_load_lds width=16 staging + dbuf counted-vmcnt (R11).
// XCD supertile swizzle: with dispatch XCD = flat%8, remap so each XCD runs
// the NY N-tiles of one M-panel consecutively -> A-panel re-reads become
// same-XCD L2 hits. Pure (m,n) permutation (bijective when NM%8==0) so
// correctness never depends on the XCD mapping. Gated: z==1 && NM%8==0.
// C/R deliberately NOT __restrict__ — O-proj writes C in-place over R.

template <int BM, int BN, int WGM, int WGN, bool ADD_RES, bool OUT_BF16>
__global__ __launch_bounds__(WGM* WGN * 64) void k_gemm_bt(
    const short* __restrict__ A, int a_zoff, int lda,
    const short* __restrict__ W, int w_zoff,
    const float* __restrict__ bias, int bias_zoff,
    short* Cb, float* Cf, int c_zoff, int ldc,
    const short* R, int ldr, int K) {
    constexpr int BK = 32;
    constexpr int WM = BM / WGM, WN = BN / WGN;
    constexpr int AM = WM / 16, AN = WN / 16;
    constexpr int NT = WGM * WGN * 64;
    constexpr int CH = (BM + BN) * (BK / 8);
    constexpr bool DBUF = (CH % NT == 0) && (CH / NT == 4);

    int tid = threadIdx.x;
    int wave = tid >> 6, lane = tid & 63;
    int wm = (wave % WGM) * WM, wn = (wave / WGM) * WN;

    int bm_idx = blockIdx.x, bn_idx = blockIdx.y;
    if (gridDim.z == 1 && (gridDim.x & 7) == 0) {
        int flat = blockIdx.x + gridDim.x * blockIdx.y;
        int k = flat & 7, l = flat >> 3;
        int j = l / gridDim.y;
        bn_idx = l - j * gridDim.y;
        bm_idx = k + 8 * j;
    }
    long m0 = (long)bm_idx * BM;
    int n0 = bn_idx * BN;
    int z = blockIdx.z;
    const short* Az = A + (long)z * a_zoff;
    const short* Wz = W + (long)z * w_zoff;

    f32x4 acc[AM][AN];
#pragma unroll
    for (int i = 0; i < AM; ++i)
#pragma unroll
        for (int j = 0; j < AN; ++j)
#pragma unroll
            for (int q = 0; q < 4; ++q) acc[i][j][q] = 0.f;

    int fr = lane & 15, ko = (lane >> 4) * 8;
    int cr = (lane >> 4) * 4, cc = lane & 15;

    if constexpr (DBUF) {
        __shared__ alignas(16) short Smem[2][(BM + BN) * BK];
        auto stage = [&](int b, int k0) {
#pragma unroll
            for (int i = 0; i < 4; ++i) {
                int c = tid + i * NT;
                int row = c >> 2, koff = (c & 3) * 8;
                const short* g = (row < BM) ? (Az + (m0 + row) * lda + k0 + koff)
                                            : (Wz + (long)(n0 + row - BM) * K + k0 + koff);
                load_lds16(g, (char*)Smem[b] + (size_t)c * 16);
            }
        };
        stage(0, 0);
        int nk = K / BK;
        for (int kt = 0; kt < nk; ++kt) {
            int b = kt & 1;
            if (kt + 1 < nk) {
                stage(b ^ 1, (kt + 1) * BK);              // 4 loads stay in flight
                asm volatile("s_waitcnt vmcnt(4)" ::: "memory");  // own tile-kt loads landed
            } else {
                asm volatile("s_waitcnt vmcnt(0)" ::: "memory");
            }
            __builtin_amdgcn_s_barrier();                  // all waves: buf b ready
            bf16x8 af[AM], bfr[AN];
#pragma unroll
            for (int i = 0; i < AM; ++i)
                af[i] = *(const bf16x8*)(&Smem[b][(wm + i * 16 + fr) * BK + ko]);
#pragma unroll
            for (int j = 0; j < AN; ++j)
                bfr[j] = *(const bf16x8*)(&Smem[b][(BM + wn + j * 16 + fr) * BK + ko]);
#pragma unroll
            for (int i = 0; i < AM; ++i)
#pragma unroll
                for (int j = 0; j < AN; ++j)
                    acc[i][j] = __builtin_amdgcn_mfma_f32_16x16x32_bf16(af[i], bfr[j], acc[i][j], 0, 0, 0);
            asm volatile("s_waitcnt lgkmcnt(0)" ::: "memory");  // reads done before overwrite
            __builtin_amdgcn_s_barrier();
        }
    } else {
        __shared__ alignas(16) short Smem[(BM + BN) * BK];
        for (int k0 = 0; k0 < K; k0 += BK) {
#pragma unroll
            for (int c = tid; c < CH; c += NT) {
                int row = c >> 2, koff = (c & 3) * 8;
                const short* g = (row < BM) ? (Az + (m0 + row) * lda + k0 + koff)
                                            : (Wz + (long)(n0 + row - BM) * K + k0 + koff);
                load_lds16(g, (char*)Smem + (size_t)c * 16);
            }
            __syncthreads();
            bf16x8 af[AM], bfr[AN];
#pragma unroll
            for (int i = 0; i < AM; ++i) af[i] = *(const bf16x8*)(&Smem[(wm + i * 16 + fr) * BK + ko]);
#pragma unroll
            for (int j = 0; j < AN; ++j) bfr[j] = *(const bf16x8*)(&Smem[(BM + wn + j * 16 + fr) * BK + ko]);
#pragma unroll
            for (int i = 0; i < AM; ++i)
#pragma unroll
                for (int j = 0; j < AN; ++j)
                    acc[i][j] = __builtin_amdgcn_mfma_f32_16x16x32_bf16(af[i], bfr[j], acc[i][j], 0, 0, 0);
            __syncthreads();
        }
    }

#pragma unroll
    for (int i = 0; i < AM; ++i) {
#pragma unroll
        for (int j = 0; j < AN; ++j) {
            int col = n0 + wn + j * 16 + cc;
            float bv = bias ? bias[(long)z * bias_zoff + col] : 0.f;
#pragma unroll
            for (int q = 0; q < 4; ++q) {
                long row = m0 + wm + i * 16 + cr + q;
                float v = acc[i][j][q] + bv;
                if constexpr (ADD_RES) v += b2f(R[row * (long)ldr + col]);
                long idx = row * (long)ldc + (long)z * c_zoff + col;
                if constexpr (OUT_BF16) Cb[idx] = f2b(v);
                else Cf[idx] = v;
            }
        }
    }
}

// ---------------- E1 GEMM with fused BN2 column-stats epilogue (dbuf) ---------

__global__ __launch_bounds__(256) void k_gemm_e1(
    const short* __restrict__ A, const short* __restrict__ W1, const float* __restrict__ beff,
    short* __restrict__ h, float* __restrict__ psum, float* __restrict__ psq) {
    constexpr int BK = 32;
    __shared__ alignas(16) short Smem[2][256 * BK];  // 32KB dbuf
    __shared__ float cS[2][128], cQ[2][128];

    int tid = threadIdx.x;
    int wave = tid >> 6, lane = tid & 63;
    int wm = (wave & 1) * 64, wn = (wave >> 1) * 64;
    long m0 = (long)blockIdx.x * 128;
    int n0 = blockIdx.y * 128;
    int z = blockIdx.z;
    const short* Wz = W1 + (long)z * 512 * 512;

    f32x4 acc[4][4];
#pragma unroll
    for (int i = 0; i < 4; ++i)
#pragma unroll
        for (int j = 0; j < 4; ++j)
#pragma unroll
            for (int q = 0; q < 4; ++q) acc[i][j][q] = 0.f;

    int fr = lane & 15, ko = (lane >> 4) * 8;

    auto stage = [&](int b, int k0) {
#pragma unroll
        for (int i = 0; i < 4; ++i) {
            int c = tid + i * 256;
            int row = c >> 2, koff = (c & 3) * 8;
            const short* g = (row < 128) ? (A + (m0 + row) * 512 + k0 + koff)
                                         : (Wz + (long)(n0 + row - 128) * 512 + k0 + koff);
            load_lds16(g, (char*)Smem[b] + (size_t)c * 16);
        }
    };
    stage(0, 0);
    for (int kt = 0; kt < 16; ++kt) {
        int b = kt & 1;
        if (kt + 1 < 16) {
            stage(b ^ 1, (kt + 1) * BK);
            asm volatile("s_waitcnt vmcnt(4)" ::: "memory");
        } else {
            asm volatile("s_waitcnt vmcnt(0)" ::: "memory");
        }
        __builtin_amdgcn_s_barrier();
        bf16x8 af[4], bfr[4];
#pragma unroll
        for (int i = 0; i < 4; ++i) af[i] = *(const bf16x8*)(&Smem[b][(wm + i * 16 + fr) * BK + ko]);
#pragma unroll
        for (int j = 0; j < 4; ++j) bfr[j] = *(const bf16x8*)(&Smem[b][(128 + wn + j * 16 + fr) * BK + ko]);
#pragma unroll
        for (int i = 0; i < 4; ++i)
#pragma unroll
            for (int j = 0; j < 4; ++j)
                acc[i][j] = __builtin_amdgcn_mfma_f32_16x16x32_bf16(af[i], bfr[j], acc[i][j], 0, 0, 0);
        asm volatile("s_waitcnt lgkmcnt(0)" ::: "memory");
        __builtin_amdgcn_s_barrier();
    }

    int cr = (lane >> 4) * 4, cc = lane & 15;
    float bv[4], colS[4], colQ[4];
#pragma unroll
    for (int j = 0; j < 4; ++j) {
        bv[j] = beff[z * 512 + n0 + wn + j * 16 + cc];
        colS[j] = 0.f; colQ[j] = 0.f;
    }
#pragma unroll
    for (int i = 0; i < 4; ++i)
#pragma unroll
        for (int j = 0; j < 4; ++j)
#pragma unroll
            for (int q = 0; q < 4; ++q) {
                float v = acc[i][j][q] + bv[j];
                acc[i][j][q] = v;
                colS[j] += v; colQ[j] += v * v;
            }
#pragma unroll
    for (int i = 0; i < 4; ++i)
#pragma unroll
        for (int q = 0; q < 4; ++q) {
            long row = m0 + wm + i * 16 + cr + q;
            short* hp = h + row * 2048 + z * 512 + n0 + wn + cc;
#pragma unroll
            for (int j = 0; j < 4; ++j) hp[j * 16] = f2b(acc[i][j][q]);
        }
#pragma unroll
    for (int j = 0; j < 4; ++j) {
        float s = colS[j], qq = colQ[j];
        s += __shfl_xor(s, 16, 64); s += __shfl_xor(s, 32, 64);
        qq += __shfl_xor(qq, 16, 64); qq += __shfl_xor(qq, 32, 64);
        if (lane < 16) { cS[wave & 1][wn + j * 16 + cc] = s; cQ[wave & 1][wn + j * 16 + cc] = qq; }
    }
    __syncthreads();
    if (tid < 128) {
        float S = cS[0][tid] + cS[1][tid];
        float Q = cQ[0][tid] + cQ[1][tid];
        psum[(long)blockIdx.x * 2048 + z * 512 + n0 + tid] = S;
        psq[(long)blockIdx.x * 2048 + z * 512 + n0 + tid] = Q;
    }
}

// ---------------- per-row attention over 4 tokens, 4 heads, hd=128 ----------------
__global__ __launch_bounds__(256) void k_attn(const short* __restrict__ qkv, short* __restrict__ ao) {
    __shared__ alignas(16) short lds[4][4][1544];
    __shared__ float attn_s[4][4][4][4];
    int w = threadIdx.x >> 6, lane = threadIdx.x & 63;
    long n = (long)blockIdx.x * 4 + w;
    const short* src = qkv + n * 4 * 1536;
#pragma unroll
    for (int c = 0; c < 12; ++c) {
        int e = c * 512 + lane * 8;
        *(bf16x8*)(&lds[w][e / 1536][e % 1536]) = *(const bf16x8*)(src + e);
    }
    __syncthreads();
    int h = lane >> 4, a = (lane >> 2) & 3, b = lane & 3;
    const short* qp = &lds[w][a][h * 128];
    const short* kp = &lds[w][b][512 + h * 128];
    float s = 0.f;
#pragma unroll
    for (int j = 0; j < 128; j += 8) {
        bf16x8 qv = *(const bf16x8*)(qp + j);
        bf16x8 kv = *(const bf16x8*)(kp + j);
#pragma unroll
        for (int x = 0; x < 8; ++x) s += b2f(qv[x]) * b2f(kv[x]);
    }
    s *= 0.08838834764831845f;
    float mx = fmaxf(s, __shfl_xor(s, 1, 64));
    mx = fmaxf(mx, __shfl_xor(mx, 2, 64));
    float e = __expf(s - mx);
    float den = e + __shfl_xor(e, 1, 64);
    den += __shfl_xor(den, 2, 64);
    attn_s[w][h][a][b] = e / den;
    __syncthreads();
    int ta = lane >> 4, cg = lane & 15;
#pragma unroll
    for (int hh = 0; hh < 4; ++hh) {
        int c0 = hh * 128 + cg * 8;
        float at0 = attn_s[w][hh][ta][0], at1 = attn_s[w][hh][ta][1];
        float at2 = attn_s[w][hh][ta][2], at3 = attn_s[w][hh][ta][3];
        bf16x8 v0 = *(const bf16x8*)(&lds[w][0][1024 + c0]);
        bf16x8 v1 = *(const bf16x8*)(&lds[w][1][1024 + c0]);
        bf16x8 v2 = *(const bf16x8*)(&lds[w][2][1024 + c0]);
        bf16x8 v3 = *(const bf16x8*)(&lds[w][3][1024 + c0]);
        bf16x8 ov;
#pragma unroll
        for (int j = 0; j < 8; ++j) {
            float val = at0 * b2f(v0[j]) + at1 * b2f(v1[j]) + at2 * b2f(v2[j]) + at3 * b2f(v3[j]);
            ov[j] = f2b(val);
        }
        *(bf16x8*)(ao + (n * 4 + ta) * 512 + c0) = ov;
    }
}

// ---------------- host ----------------

extern "C" void kernel_launch(void* const* d_in, const int* in_sizes, int n_in,
                              void* d_out, int out_size, void* d_ws, size_t ws_size,
                              hipStream_t stream) {
    const float* x = (const float*)d_in[0];
    const float* bn1_g = (const float*)d_in[1];
    const float* bn1_b = (const float*)d_in[2];
    const float* w1 = (const float*)d_in[3];
    const float* bn2_g = (const float*)d_in[4];
    const float* bn2_b = (const float*)d_in[5];
    const float* wq = (const float*)d_in[6];
    const float* bq = (const float*)d_in[7];
    const float* wk = (const float*)d_in[8];
    const float* bk = (const float*)d_in[9];
    const float* wv = (const float*)d_in[10];
    const float* bv = (const float*)d_in[11];
    const float* wo = (const float*)d_in[12];
    const float* bo = (const float*)d_in[13];
    const float* ln1_g = (const float*)d_in[14];
    const float* ln1_b = (const float*)d_in[15];
    const float* wff = (const float*)d_in[16];
    const float* bff = (const float*)d_in[17];
    const float* ln2_g = (const float*)d_in[18];
    const float* ln2_b = (const float*)d_in[19];
    const float* w2 = (const float*)d_in[20];
    const float* bn3_g = (const float*)d_in[21];
    const float* bn3_b = (const float*)d_in[22];
    float* out = (float*)d_out;

    char* ws = (char*)d_ws;
    size_t off = 0;
    auto alloc = [&](size_t bytes) {
        void* p = ws + off;
        off = (off + bytes + 255) & ~(size_t)255;
        return p;
    };

    // ---- fixed allocations (~82 MB) ----
    short* W1b = (short*)alloc(4l * 512 * 512 * 2);
    float* beff = (float*)alloc(4l * 512 * 4);
    short* Wqkvb = (short*)alloc(1536l * 512 * 2);
    float* bqkv = (float*)alloc(1536l * 4);
    short* wo_b = (short*)alloc(512l * 512 * 2);
    short* wff_b = (short*)alloc(512l * 512 * 2);
    short* w2_b = (short*)alloc(4l * 32 * 512 * 2);
    float* mean1 = (float*)alloc(512 * 4);
    float* rs1 = (float*)alloc(512 * 4);
    float* scale2 = (float*)alloc(2048 * 4);
    float* shift2 = (float*)alloc(2048 * 4);
    float* scale3 = (float*)alloc(128 * 4);
    float* shift3 = (float*)alloc(128 * 4);
    float* psum1 = (float*)alloc(256l * 512 * 4);
    float* psq1 = (float*)alloc(256l * 512 * 4);
    float* psum2 = (float*)alloc(128l * 2048 * 4);
    float* psq2 = (float*)alloc(128l * 2048 * 4);
    float* psum3 = (float*)alloc(256l * 128 * 4);
    float* psq3 = (float*)alloc(256l * 128 * 4);
    short* slotA = (short*)alloc(16384l * 2048 * 2);  // h -> t -> a1 (in-place)
    float* out_pre = (float*)alloc(16384l * 128 * 4);
    short* bufB = (short*)alloc(16384l * 2048 * 2);   // xb -> attn_o -> a2 (64 MB)

    // ---- qkv chunk arena: NCq batch-rows (qkv only) ----
    long NCq = 1024;
    for (long cand = 8192; cand >= 1024; cand >>= 1) {
        if (off + (size_t)cand * 12288 + (1u << 20) <= ws_size) { NCq = cand; break; }
    }
    short* qkv_c = (short*)alloc((size_t)NCq * 12288);
    short* xb = bufB;  // 16 MB input cast lives in bufB until E1 consumes it

    dim3 B256(256);

    // prep + x cast/stats
    hipLaunchKernelGGL(k_prep, dim3(678), B256, 0, stream,
                       wq, wk, wv, wo, wff, w2, bq, bk, bv,
                       Wqkvb, wo_b, wff_b, w2_b, bqkv);
    hipLaunchKernelGGL(k_statcast_x, dim3(256), B256, 0, stream, x, xb, psum1, psq1);

    // BN1 finalize + fold into E1 weights
    hipLaunchKernelGGL(k_finalize_meanrs, dim3(8), B256, 0, stream, psum1, psq1, 256, 512,
                       1.f / 16384.f, mean1, rs1);
    hipLaunchKernelGGL(k_fold_w1, dim3(2048), B256, 0, stream, w1, bn1_g, bn1_b, mean1, rs1, W1b, beff);

    // E1 + fused BN2 partial stats (xb in bufB; h -> slotA)
    hipLaunchKernelGGL(k_gemm_e1, dim3(128, 4, 4), B256, 0, stream,
                       xb, W1b, beff, slotA, psum2, psq2);

    // BN2 finalize + sigmoid -> t (in-place in slotA)
    hipLaunchKernelGGL(k_finalize_ss, dim3(32), B256, 0, stream, psum2, psq2, 128, 2048,
                       1.f / 16384.f, bn2_g, bn2_b, scale2, shift2);
    hipLaunchKernelGGL(k_bnsig, dim3(16384), B256, 0, stream, slotA, slotA, scale2, shift2);

    // ---- QKV + attention (chunked for workspace; attn_o -> bufB) ----
    long nch = 16384 / NCq;
    for (long c = 0; c < nch; ++c) {
        long r0 = c * NCq;
        const short* t_c = slotA + r0 * 2048;
        int gx = (int)(NCq * 4 / 128);

        hipLaunchKernelGGL((k_gemm_bt<128, 128, 2, 2, false, true>), dim3(gx, 12, 1), B256, 0, stream,
                           t_c, 0, 512, Wqkvb, 0, bqkv, 0,
                           qkv_c, (float*)nullptr, 0, 1536, (const short*)nullptr, 0, 512);

        hipLaunchKernelGGL(k_attn, dim3((int)(NCq / 4)), B256, 0, stream,
                           qkv_c, bufB + r0 * 2048);
    }

    // ---- full-batch tail ----
    // O-proj + bias + residual t, IN-PLACE over t (slotA) -> a1pre
    hipLaunchKernelGGL((k_gemm_bt<128, 128, 2, 2, true, true>), dim3(512, 4, 1), B256, 0, stream,
                       bufB, 0, 512, wo_b, 0, bo, 0,
                       slotA, (float*)nullptr, 0, 512, slotA, 512, 512);

    // LN1 in-place (slotA = a1)
    hipLaunchKernelGGL(k_ln, dim3(16384), B256, 0, stream, slotA, slotA, ln1_g, ln1_b);

    // FF + bias + residual a1 -> a2pre (bufB; attn data dead)
    hipLaunchKernelGGL((k_gemm_bt<128, 128, 2, 2, true, true>), dim3(512, 4, 1), B256, 0, stream,
                       slotA, 0, 512, wff_b, 0, bff, 0,
                       bufB, (float*)nullptr, 0, 512, slotA, 512, 512);

    // LN2 in-place (bufB = a2)
    hipLaunchKernelGGL(k_ln, dim3(16384), B256, 0, stream, bufB, bufB, ln2_g, ln2_b);

    // E2: per-detector [16384,512] @ [32,512]^T -> out_pre (f32)
    hipLaunchKernelGGL((k_gemm_bt<128, 32, 4, 1, false, false>), dim3(128, 1, 4), B256, 0, stream,
                       bufB, 512, 2048, w2_b, 32 * 512, (const float*)nullptr, 0,
                       (short*)nullptr, out_pre, 32, 128, (const short*)nullptr, 0, 512);

    // BN3 + sigmoid -> out
    hipLaunchKernelGGL(k_stats_o, dim3(128), B256, 0, stream, out_pre, psum3, psq3);
    hipLaunchKernelGGL(k_finalize_ss, dim3(2), B256, 0, stream, psum3, psq3, 256, 128,
                       1.f / 16384.f, bn3_g, bn3_b, scale3, shift3);
    hipLaunchKernelGGL(k_bn3sig, dim3(2048), B256, 0, stream, out_pre, out, scale3, shift3);
}

// Round 13
// 551.276 us; speedup vs baseline: 1.2754x; 1.0433x over previous
//
#include <hip/hip_runtime.h>
#include <hip/hip_bf16.h>

#define EPS 1e-5f

typedef __attribute__((ext_vector_type(8))) short bf16x8;
typedef __attribute__((ext_vector_type(4))) float f32x4;
typedef __attribute__((ext_vector_type(4))) float float4v;

__device__ __forceinline__ float b2f(short u) {
    union { unsigned int i; float f; } x;
    x.i = ((unsigned int)(unsigned short)u) << 16;
    return x.f;
}
__device__ __forceinline__ short f2b(float f) {
    unsigned int x = __builtin_bit_cast(unsigned int, f);
    unsigned int r = (x + 0x7FFFu + ((x >> 16) & 1u)) >> 16;
    return (short)r;
}

__device__ __forceinline__ void load_lds16(const void* g, void* l) {
    __builtin_amdgcn_global_load_lds(
        (const __attribute__((address_space(1))) unsigned int*)g,
        (__attribute__((address_space(3))) unsigned int*)l, 16, 0, 0);
}

// ---------------- fused weight prep: 5 big casts + w2 cast + bias concat -----

__device__ __forceinline__ void cast8(const float* __restrict__ src, short* __restrict__ dst, long idx) {
    const float4v* s = (const float4v*)src;
    float4v a = s[idx * 2], b = s[idx * 2 + 1];
    bf16x8 o;
    o[0] = f2b(a[0]); o[1] = f2b(a[1]); o[2] = f2b(a[2]); o[3] = f2b(a[3]);
    o[4] = f2b(b[0]); o[5] = f2b(b[1]); o[6] = f2b(b[2]); o[7] = f2b(b[3]);
    *(bf16x8*)(dst + idx * 8) = o;
}

__global__ __launch_bounds__(256) void k_prep(
    const float* __restrict__ wq, const float* __restrict__ wk, const float* __restrict__ wv,
    const float* __restrict__ wo, const float* __restrict__ wff, const float* __restrict__ w2,
    const float* __restrict__ bq, const float* __restrict__ bk, const float* __restrict__ bv,
    short* __restrict__ Wqkvb, short* __restrict__ wo_b, short* __restrict__ wff_b,
    short* __restrict__ w2_b, float* __restrict__ bqkv) {
    int bid = blockIdx.x, tid = threadIdx.x;
    if (bid < 640) {
        int seg = bid >> 7;
        long idx = (long)(bid & 127) * 256 + tid;
        const float* src;
        short* dst;
        if (seg == 0) { src = wq; dst = Wqkvb; }
        else if (seg == 1) { src = wk; dst = Wqkvb + 262144; }
        else if (seg == 2) { src = wv; dst = Wqkvb + 524288; }
        else if (seg == 3) { src = wo; dst = wo_b; }
        else { src = wff; dst = wff_b; }
        cast8(src, dst, idx);
    } else if (bid < 672) {
        long idx = (long)(bid - 640) * 256 + tid;
        cast8(w2, w2_b, idx);
    } else {
        int i = (bid - 672) * 256 + tid;
        if (i < 512) bqkv[i] = bq[i];
        else if (i < 1024) bqkv[i] = bk[i - 512];
        else if (i < 1536) bqkv[i] = bv[i - 1024];
    }
}

// fused: per-column stats of x [16384,512] + bf16 cast. block = 64 rows.
__global__ __launch_bounds__(256) void k_statcast_x(const float* __restrict__ x,
                                                    short* __restrict__ xb,
                                                    float* __restrict__ psum, float* __restrict__ psq) {
    int b = blockIdx.x, tid = threadIdx.x;
    const float* xp = x + (long)b * 64 * 512;
    short* xo = xb + (long)b * 64 * 512;
    float s0 = 0, q0 = 0, s1 = 0, q1 = 0;
    for (int r = 0; r < 64; ++r) {
        float v0 = xp[r * 512 + tid];
        float v1 = xp[r * 512 + tid + 256];
        xo[r * 512 + tid] = f2b(v0);
        xo[r * 512 + tid + 256] = f2b(v1);
        s0 += v0; q0 += v0 * v0; s1 += v1; q1 += v1 * v1;
    }
    psum[b * 512 + tid] = s0; psum[b * 512 + tid + 256] = s1;
    psq[b * 512 + tid] = q0;  psq[b * 512 + tid + 256] = q1;
}

// ---- parallel finalize: grid = ncols/64, block = 4 part-groups x 64 cols ----

__global__ __launch_bounds__(256) void k_finalize_meanrs(const float* __restrict__ psum,
                                                         const float* __restrict__ psq,
                                                         int nparts, int ncols, float invB,
                                                         float* __restrict__ mean, float* __restrict__ rs) {
    int l = threadIdx.x & 63, grp = threadIdx.x >> 6;
    int c = blockIdx.x * 64 + l;
    float s = 0, q = 0;
    for (int p = grp; p < nparts; p += 4) {
        s += psum[(long)p * ncols + c];
        q += psq[(long)p * ncols + c];
    }
    __shared__ float rs_[4][64], rq_[4][64];
    rs_[grp][l] = s; rq_[grp][l] = q;
    __syncthreads();
    if (grp == 0) {
        s = rs_[0][l] + rs_[1][l] + rs_[2][l] + rs_[3][l];
        q = rq_[0][l] + rq_[1][l] + rq_[2][l] + rq_[3][l];
        float m = s * invB;
        float v = q * invB - m * m;
        mean[c] = m;
        rs[c] = rsqrtf(v + EPS);
    }
}

__global__ __launch_bounds__(256) void k_finalize_ss(const float* __restrict__ psum,
                                                     const float* __restrict__ psq,
                                                     int nparts, int ncols, float invB,
                                                     const float* __restrict__ g, const float* __restrict__ bb,
                                                     float* __restrict__ scale, float* __restrict__ shift) {
    int l = threadIdx.x & 63, grp = threadIdx.x >> 6;
    int c = blockIdx.x * 64 + l;
    float s = 0, q = 0;
    for (int p = grp; p < nparts; p += 4) {
        s += psum[(long)p * ncols + c];
        q += psq[(long)p * ncols + c];
    }
    __shared__ float rs_[4][64], rq_[4][64];
    rs_[grp][l] = s; rq_[grp][l] = q;
    __syncthreads();
    if (grp == 0) {
        s = rs_[0][l] + rs_[1][l] + rs_[2][l] + rs_[3][l];
        q = rq_[0][l] + rq_[1][l] + rq_[2][l] + rq_[3][l];
        float m = s * invB, v = q * invB - m * m;
        float sc = g[c] * rsqrtf(v + EPS);
        scale[c] = sc;
        shift[c] = bb[c] - m * sc;
    }
}

// fold BN1 into w1: block = one (d,o) row
__global__ __launch_bounds__(256) void k_fold_w1(const float* __restrict__ w1, const float* __restrict__ g1,
                                                 const float* __restrict__ b1, const float* __restrict__ mean,
                                                 const float* __restrict__ rs,
                                                 short* __restrict__ W1b, float* __restrict__ beff) {
    int bx = blockIdx.x;  // d*512 + o
    int d = bx >> 9, tid = threadIdx.x;
    const float* wrow = w1 + (long)bx * 512;
    float part = 0.f;
    for (int i = tid; i < 512; i += 256) {
        float wv = wrow[i];
        float sc = rs[i] * g1[d * 512 + i];
        W1b[(long)bx * 512 + i] = f2b(wv * sc);
        part += (b1[d * 512 + i] - mean[i] * sc) * wv;
    }
    __shared__ float red[256];
    red[tid] = part;
    __syncthreads();
    for (int st = 128; st > 0; st >>= 1) {
        if (tid < st) red[tid] += red[tid + st];
        __syncthreads();
    }
    if (tid == 0) beff[bx] = red[0];
}

// t = sigmoid(h*scale + shift), bf16, in-place safe (elementwise same-index)
__global__ __launch_bounds__(256) void k_bnsig(const short* h, short* t,
                                               const float* __restrict__ scale,
                                               const float* __restrict__ shift) {
    long i8 = ((long)blockIdx.x * 256 + threadIdx.x) * 8;
    int c0 = (int)(i8 & 2047);
    bf16x8 v = *(const bf16x8*)(h + i8);
    bf16x8 o;
#pragma unroll
    for (int j = 0; j < 8; ++j) {
        float x = b2f(v[j]) * scale[c0 + j] + shift[c0 + j];
        o[j] = f2b(1.f / (1.f + __expf(-x)));
    }
    *(bf16x8*)(t + i8) = o;
}

// LayerNorm over last dim 512, one wave per token; in-place safe
__global__ __launch_bounds__(256) void k_ln(const short* in, short* out,
                                            const float* __restrict__ g, const float* __restrict__ bb) {
    int w = threadIdx.x >> 6, lane = threadIdx.x & 63;
    long row = (long)blockIdx.x * 4 + w;
    const short* rp = in + row * 512;
    bf16x8 v = *(const bf16x8*)(rp + lane * 8);
    float f[8];
    float s = 0.f;
#pragma unroll
    for (int j = 0; j < 8; ++j) { f[j] = b2f(v[j]); s += f[j]; }
#pragma unroll
    for (int m = 1; m < 64; m <<= 1) s += __shfl_xor(s, m, 64);
    float mean = s * (1.f / 512.f);
    float q = 0.f;
#pragma unroll
    for (int j = 0; j < 8; ++j) { float d = f[j] - mean; q += d * d; }
#pragma unroll
    for (int m = 1; m < 64; m <<= 1) q += __shfl_xor(q, m, 64);
    float rs = rsqrtf(q * (1.f / 512.f) + EPS);
    bf16x8 o;
#pragma unroll
    for (int j = 0; j < 8; ++j) {
        int c = lane * 8 + j;
        o[j] = f2b((f[j] - mean) * rs * g[c] + bb[c]);
    }
    *(bf16x8*)(out + row * 512 + lane * 8) = o;
}

__global__ __launch_bounds__(256) void k_bn3sig(const float* __restrict__ pre, float* __restrict__ out,
                                                const float* __restrict__ scale, const float* __restrict__ shift) {
    long i4 = ((long)blockIdx.x * 256 + threadIdx.x) * 4;
    float4v v = *(const float4v*)(pre + i4);
    int c0 = (int)(i4 & 127);
    float4v o;
#pragma unroll
    for (int j = 0; j < 4; ++j) {
        float x = v[j] * scale[c0 + j] + shift[c0 + j];
        o[j] = 1.f / (1.f + __expf(-x));
    }
    *(float4v*)(out + i4) = o;
}

// ---------------- MFMA GEMM: C = A @ W^T (+bias)(+residual) ----------------
// global_load_lds width=16 staging + dbuf counted-vmcnt (R11).
// XCD supertile swizzle (R12, verified: FETCH 160->70 MB on O/FF): with
// dispatch XCD = flat%8, remap so each XCD runs the NY N-tiles of one M-panel
// consecutively -> A-panel re-reads become same-XCD L2 hits. Pure permutation
// (bijective when NM%8==0); gated: z==1 && NM%8==0.
// C/R deliberately NOT __restrict__ — O-proj writes C in-place over R.

template <int BM, int BN, int WGM, int WGN, bool ADD_RES, bool OUT_BF16>
__global__ __launch_bounds__(WGM* WGN * 64) void k_gemm_bt(
    const short* __restrict__ A, int a_zoff, int lda,
    const short* __restrict__ W, int w_zoff,
    const float* __restrict__ bias, int bias_zoff,
    short* Cb, float* Cf, int c_zoff, int ldc,
    const short* R, int ldr, int K) {
    constexpr int BK = 32;
    constexpr int WM = BM / WGM, WN = BN / WGN;
    constexpr int AM = WM / 16, AN = WN / 16;
    constexpr int NT = WGM * WGN * 64;
    constexpr int CH = (BM + BN) * (BK / 8);
    constexpr bool DBUF = (CH % NT == 0) && (CH / NT == 4);

    int tid = threadIdx.x;
    int wave = tid >> 6, lane = tid & 63;
    int wm = (wave % WGM) * WM, wn = (wave / WGM) * WN;

    int bm_idx = blockIdx.x, bn_idx = blockIdx.y;
    if (gridDim.z == 1 && (gridDim.x & 7) == 0) {
        int flat = blockIdx.x + gridDim.x * blockIdx.y;
        int k = flat & 7, l = flat >> 3;
        int j = l / gridDim.y;
        bn_idx = l - j * gridDim.y;
        bm_idx = k + 8 * j;
    }
    long m0 = (long)bm_idx * BM;
    int n0 = bn_idx * BN;
    int z = blockIdx.z;
    const short* Az = A + (long)z * a_zoff;
    const short* Wz = W + (long)z * w_zoff;

    f32x4 acc[AM][AN];
#pragma unroll
    for (int i = 0; i < AM; ++i)
#pragma unroll
        for (int j = 0; j < AN; ++j)
#pragma unroll
            for (int q = 0; q < 4; ++q) acc[i][j][q] = 0.f;

    int fr = lane & 15, ko = (lane >> 4) * 8;
    int cr = (lane >> 4) * 4, cc = lane & 15;

    if constexpr (DBUF) {
        __shared__ alignas(16) short Smem[2][(BM + BN) * BK];
        auto stage = [&](int b, int k0) {
#pragma unroll
            for (int i = 0; i < 4; ++i) {
                int c = tid + i * NT;
                int row = c >> 2, koff = (c & 3) * 8;
                const short* g = (row < BM) ? (Az + (m0 + row) * lda + k0 + koff)
                                            : (Wz + (long)(n0 + row - BM) * K + k0 + koff);
                load_lds16(g, (char*)Smem[b] + (size_t)c * 16);
            }
        };
        stage(0, 0);
        int nk = K / BK;
        for (int kt = 0; kt < nk; ++kt) {
            int b = kt & 1;
            if (kt + 1 < nk) {
                stage(b ^ 1, (kt + 1) * BK);              // 4 loads stay in flight
                asm volatile("s_waitcnt vmcnt(4)" ::: "memory");  // own tile-kt loads landed
            } else {
                asm volatile("s_waitcnt vmcnt(0)" ::: "memory");
            }
            __builtin_amdgcn_s_barrier();                  // all waves: buf b ready
            bf16x8 af[AM], bfr[AN];
#pragma unroll
            for (int i = 0; i < AM; ++i)
                af[i] = *(const bf16x8*)(&Smem[b][(wm + i * 16 + fr) * BK + ko]);
#pragma unroll
            for (int j = 0; j < AN; ++j)
                bfr[j] = *(const bf16x8*)(&Smem[b][(BM + wn + j * 16 + fr) * BK + ko]);
#pragma unroll
            for (int i = 0; i < AM; ++i)
#pragma unroll
                for (int j = 0; j < AN; ++j)
                    acc[i][j] = __builtin_amdgcn_mfma_f32_16x16x32_bf16(af[i], bfr[j], acc[i][j], 0, 0, 0);
            asm volatile("s_waitcnt lgkmcnt(0)" ::: "memory");  // reads done before overwrite
            __builtin_amdgcn_s_barrier();
        }
    } else {
        __shared__ alignas(16) short Smem[(BM + BN) * BK];
        for (int k0 = 0; k0 < K; k0 += BK) {
#pragma unroll
            for (int c = tid; c < CH; c += NT) {
                int row = c >> 2, koff = (c & 3) * 8;
                const short* g = (row < BM) ? (Az + (m0 + row) * lda + k0 + koff)
                                            : (Wz + (long)(n0 + row - BM) * K + k0 + koff);
                load_lds16(g, (char*)Smem + (size_t)c * 16);
            }
            __syncthreads();
            bf16x8 af[AM], bfr[AN];
#pragma unroll
            for (int i = 0; i < AM; ++i) af[i] = *(const bf16x8*)(&Smem[(wm + i * 16 + fr) * BK + ko]);
#pragma unroll
            for (int j = 0; j < AN; ++j) bfr[j] = *(const bf16x8*)(&Smem[(BM + wn + j * 16 + fr) * BK + ko]);
#pragma unroll
            for (int i = 0; i < AM; ++i)
#pragma unroll
                for (int j = 0; j < AN; ++j)
                    acc[i][j] = __builtin_amdgcn_mfma_f32_16x16x32_bf16(af[i], bfr[j], acc[i][j], 0, 0, 0);
            __syncthreads();
        }
    }

#pragma unroll
    for (int i = 0; i < AM; ++i) {
#pragma unroll
        for (int j = 0; j < AN; ++j) {
            int col = n0 + wn + j * 16 + cc;
            float bv = bias ? bias[(long)z * bias_zoff + col] : 0.f;
#pragma unroll
            for (int q = 0; q < 4; ++q) {
                long row = m0 + wm + i * 16 + cr + q;
                float v = acc[i][j][q] + bv;
                if constexpr (ADD_RES) v += b2f(R[row * (long)ldr + col]);
                long idx = row * (long)ldc + (long)z * c_zoff + col;
                if constexpr (OUT_BF16) Cb[idx] = f2b(v);
                else Cf[idx] = v;
            }
        }
    }
}

// ---------------- E1 GEMM with fused BN2 column-stats epilogue (dbuf) ---------

__global__ __launch_bounds__(256) void k_gemm_e1(
    const short* __restrict__ A, const short* __restrict__ W1, const float* __restrict__ beff,
    short* __restrict__ h, float* __restrict__ psum, float* __restrict__ psq) {
    constexpr int BK = 32;
    __shared__ alignas(16) short Smem[2][256 * BK];  // 32KB dbuf
    __shared__ float cS[2][128], cQ[2][128];

    int tid = threadIdx.x;
    int wave = tid >> 6, lane = tid & 63;
    int wm = (wave & 1) * 64, wn = (wave >> 1) * 64;
    long m0 = (long)blockIdx.x * 128;
    int n0 = blockIdx.y * 128;
    int z = blockIdx.z;
    const short* Wz = W1 + (long)z * 512 * 512;

    f32x4 acc[4][4];
#pragma unroll
    for (int i = 0; i < 4; ++i)
#pragma unroll
        for (int j = 0; j < 4; ++j)
#pragma unroll
            for (int q = 0; q < 4; ++q) acc[i][j][q] = 0.f;

    int fr = lane & 15, ko = (lane >> 4) * 8;

    auto stage = [&](int b, int k0) {
#pragma unroll
        for (int i = 0; i < 4; ++i) {
            int c = tid + i * 256;
            int row = c >> 2, koff = (c & 3) * 8;
            const short* g = (row < 128) ? (A + (m0 + row) * 512 + k0 + koff)
                                         : (Wz + (long)(n0 + row - 128) * 512 + k0 + koff);
            load_lds16(g, (char*)Smem[b] + (size_t)c * 16);
        }
    };
    stage(0, 0);
    for (int kt = 0; kt < 16; ++kt) {
        int b = kt & 1;
        if (kt + 1 < 16) {
            stage(b ^ 1, (kt + 1) * BK);
            asm volatile("s_waitcnt vmcnt(4)" ::: "memory");
        } else {
            asm volatile("s_waitcnt vmcnt(0)" ::: "memory");
        }
        __builtin_amdgcn_s_barrier();
        bf16x8 af[4], bfr[4];
#pragma unroll
        for (int i = 0; i < 4; ++i) af[i] = *(const bf16x8*)(&Smem[b][(wm + i * 16 + fr) * BK + ko]);
#pragma unroll
        for (int j = 0; j < 4; ++j) bfr[j] = *(const bf16x8*)(&Smem[b][(128 + wn + j * 16 + fr) * BK + ko]);
#pragma unroll
        for (int i = 0; i < 4; ++i)
#pragma unroll
            for (int j = 0; j < 4; ++j)
                acc[i][j] = __builtin_amdgcn_mfma_f32_16x16x32_bf16(af[i], bfr[j], acc[i][j], 0, 0, 0);
        asm volatile("s_waitcnt lgkmcnt(0)" ::: "memory");
        __builtin_amdgcn_s_barrier();
    }

    int cr = (lane >> 4) * 4, cc = lane & 15;
    float bv[4], colS[4], colQ[4];
#pragma unroll
    for (int j = 0; j < 4; ++j) {
        bv[j] = beff[z * 512 + n0 + wn + j * 16 + cc];
        colS[j] = 0.f; colQ[j] = 0.f;
    }
#pragma unroll
    for (int i = 0; i < 4; ++i)
#pragma unroll
        for (int j = 0; j < 4; ++j)
#pragma unroll
            for (int q = 0; q < 4; ++q) {
                float v = acc[i][j][q] + bv[j];
                acc[i][j][q] = v;
                colS[j] += v; colQ[j] += v * v;
            }
#pragma unroll
    for (int i = 0; i < 4; ++i)
#pragma unroll
        for (int q = 0; q < 4; ++q) {
            long row = m0 + wm + i * 16 + cr + q;
            short* hp = h + row * 2048 + z * 512 + n0 + wn + cc;
#pragma unroll
            for (int j = 0; j < 4; ++j) hp[j * 16] = f2b(acc[i][j][q]);
        }
#pragma unroll
    for (int j = 0; j < 4; ++j) {
        float s = colS[j], qq = colQ[j];
        s += __shfl_xor(s, 16, 64); s += __shfl_xor(s, 32, 64);
        qq += __shfl_xor(qq, 16, 64); qq += __shfl_xor(qq, 32, 64);
        if (lane < 16) { cS[wave & 1][wn + j * 16 + cc] = s; cQ[wave & 1][wn + j * 16 + cc] = qq; }
    }
    __syncthreads();
    if (tid < 128) {
        float S = cS[0][tid] + cS[1][tid];
        float Q = cQ[0][tid] + cQ[1][tid];
        psum[(long)blockIdx.x * 2048 + z * 512 + n0 + tid] = S;
        psq[(long)blockIdx.x * 2048 + z * 512 + n0 + tid] = Q;
    }
}

// ---------------- E2 GEMM (per-detector, f32 out) + fused BN3 column stats ----
// grid (128 M-tiles, 1, 4 z). BM=128, BN=32, 4 waves (WGN=1 -> all waves share
// cols). Column partials over the block's 128 rows -> psum3[mtile][z*32+c].

__global__ __launch_bounds__(256) void k_gemm_e2(
    const short* __restrict__ A, int a_zoff, int lda,
    const short* __restrict__ W2,
    float* __restrict__ Cf, int ldc,
    float* __restrict__ psum, float* __restrict__ psq) {
    constexpr int BK = 32;
    __shared__ alignas(16) short Smem[(128 + 32) * BK];
    __shared__ float cS[4][32], cQ[4][32];

    int tid = threadIdx.x;
    int wave = tid >> 6, lane = tid & 63;
    int wm = wave * 32;
    long m0 = (long)blockIdx.x * 128;
    int z = blockIdx.z;
    const short* Az = A + (long)z * a_zoff;
    const short* Wz = W2 + (long)z * 32 * 512;

    f32x4 acc[2][2];
#pragma unroll
    for (int i = 0; i < 2; ++i)
#pragma unroll
        for (int j = 0; j < 2; ++j)
#pragma unroll
            for (int q = 0; q < 4; ++q) acc[i][j][q] = 0.f;

    int fr = lane & 15, ko = (lane >> 4) * 8;

    for (int k0 = 0; k0 < 512; k0 += BK) {
        for (int c = tid; c < 640; c += 256) {
            int row = c >> 2, koff = (c & 3) * 8;
            const short* g = (row < 128) ? (Az + (m0 + row) * lda + k0 + koff)
                                         : (Wz + (long)(row - 128) * 512 + k0 + koff);
            load_lds16(g, (char*)Smem + (size_t)c * 16);
        }
        __syncthreads();
        bf16x8 af[2], bfr[2];
#pragma unroll
        for (int i = 0; i < 2; ++i) af[i] = *(const bf16x8*)(&Smem[(wm + i * 16 + fr) * BK + ko]);
#pragma unroll
        for (int j = 0; j < 2; ++j) bfr[j] = *(const bf16x8*)(&Smem[(128 + j * 16 + fr) * BK + ko]);
#pragma unroll
        for (int i = 0; i < 2; ++i)
#pragma unroll
            for (int j = 0; j < 2; ++j)
                acc[i][j] = __builtin_amdgcn_mfma_f32_16x16x32_bf16(af[i], bfr[j], acc[i][j], 0, 0, 0);
        __syncthreads();
    }

    int cr = (lane >> 4) * 4, cc = lane & 15;
    float colS[2] = {0.f, 0.f}, colQ[2] = {0.f, 0.f};
#pragma unroll
    for (int i = 0; i < 2; ++i)
#pragma unroll
        for (int q = 0; q < 4; ++q) {
            long row = m0 + wm + i * 16 + cr + q;
            float* cp = Cf + row * (long)ldc + z * 32 + cc;
#pragma unroll
            for (int j = 0; j < 2; ++j) {
                float v = acc[i][j][q];
                cp[j * 16] = v;
                colS[j] += v; colQ[j] += v * v;
            }
        }
#pragma unroll
    for (int j = 0; j < 2; ++j) {
        float s = colS[j], qq = colQ[j];
        s += __shfl_xor(s, 16, 64); s += __shfl_xor(s, 32, 64);
        qq += __shfl_xor(qq, 16, 64); qq += __shfl_xor(qq, 32, 64);
        if (lane < 16) { cS[wave][j * 16 + cc] = s; cQ[wave][j * 16 + cc] = qq; }
    }
    __syncthreads();
    if (tid < 32) {
        float S = cS[0][tid] + cS[1][tid] + cS[2][tid] + cS[3][tid];
        float Q = cQ[0][tid] + cQ[1][tid] + cQ[2][tid] + cQ[3][tid];
        psum[(long)blockIdx.x * 128 + z * 32 + tid] = S;
        psq[(long)blockIdx.x * 128 + z * 32 + tid] = Q;
    }
}

// ---------------- per-row attention over 4 tokens, 4 heads, hd=128 ----------------
__global__ __launch_bounds__(256) void k_attn(const short* __restrict__ qkv, short* __restrict__ ao) {
    __shared__ alignas(16) short lds[4][4][1544];
    __shared__ float attn_s[4][4][4][4];
    int w = threadIdx.x >> 6, lane = threadIdx.x & 63;
    long n = (long)blockIdx.x * 4 + w;
    const short* src = qkv + n * 4 * 1536;
#pragma unroll
    for (int c = 0; c < 12; ++c) {
        int e = c * 512 + lane * 8;
        *(bf16x8*)(&lds[w][e / 1536][e % 1536]) = *(const bf16x8*)(src + e);
    }
    __syncthreads();
    int h = lane >> 4, a = (lane >> 2) & 3, b = lane & 3;
    const short* qp = &lds[w][a][h * 128];
    const short* kp = &lds[w][b][512 + h * 128];
    float s = 0.f;
#pragma unroll
    for (int j = 0; j < 128; j += 8) {
        bf16x8 qv = *(const bf16x8*)(qp + j);
        bf16x8 kv = *(const bf16x8*)(kp + j);
#pragma unroll
        for (int x = 0; x < 8; ++x) s += b2f(qv[x]) * b2f(kv[x]);
    }
    s *= 0.08838834764831845f;
    float mx = fmaxf(s, __shfl_xor(s, 1, 64));
    mx = fmaxf(mx, __shfl_xor(mx, 2, 64));
    float e = __expf(s - mx);
    float den = e + __shfl_xor(e, 1, 64);
    den += __shfl_xor(den, 2, 64);
    attn_s[w][h][a][b] = e / den;
    __syncthreads();
    int ta = lane >> 4, cg = lane & 15;
#pragma unroll
    for (int hh = 0; hh < 4; ++hh) {
        int c0 = hh * 128 + cg * 8;
        float at0 = attn_s[w][hh][ta][0], at1 = attn_s[w][hh][ta][1];
        float at2 = attn_s[w][hh][ta][2], at3 = attn_s[w][hh][ta][3];
        bf16x8 v0 = *(const bf16x8*)(&lds[w][0][1024 + c0]);
        bf16x8 v1 = *(const bf16x8*)(&lds[w][1][1024 + c0]);
        bf16x8 v2 = *(const bf16x8*)(&lds[w][2][1024 + c0]);
        bf16x8 v3 = *(const bf16x8*)(&lds[w][3][1024 + c0]);
        bf16x8 ov;
#pragma unroll
        for (int j = 0; j < 8; ++j) {
            float val = at0 * b2f(v0[j]) + at1 * b2f(v1[j]) + at2 * b2f(v2[j]) + at3 * b2f(v3[j]);
            ov[j] = f2b(val);
        }
        *(bf16x8*)(ao + (n * 4 + ta) * 512 + c0) = ov;
    }
}

// ---------------- host ----------------

extern "C" void kernel_launch(void* const* d_in, const int* in_sizes, int n_in,
                              void* d_out, int out_size, void* d_ws, size_t ws_size,
                              hipStream_t stream) {
    const float* x = (const float*)d_in[0];
    const float* bn1_g = (const float*)d_in[1];
    const float* bn1_b = (const float*)d_in[2];
    const float* w1 = (const float*)d_in[3];
    const float* bn2_g = (const float*)d_in[4];
    const float* bn2_b = (const float*)d_in[5];
    const float* wq = (const float*)d_in[6];
    const float* bq = (const float*)d_in[7];
    const float* wk = (const float*)d_in[8];
    const float* bk = (const float*)d_in[9];
    const float* wv = (const float*)d_in[10];
    const float* bv = (const float*)d_in[11];
    const float* wo = (const float*)d_in[12];
    const float* bo = (const float*)d_in[13];
    const float* ln1_g = (const float*)d_in[14];
    const float* ln1_b = (const float*)d_in[15];
    const float* wff = (const float*)d_in[16];
    const float* bff = (const float*)d_in[17];
    const float* ln2_g = (const float*)d_in[18];
    const float* ln2_b = (const float*)d_in[19];
    const float* w2 = (const float*)d_in[20];
    const float* bn3_g = (const float*)d_in[21];
    const float* bn3_b = (const float*)d_in[22];
    float* out = (float*)d_out;

    char* ws = (char*)d_ws;
    size_t off = 0;
    auto alloc = [&](size_t bytes) {
        void* p = ws + off;
        off = (off + bytes + 255) & ~(size_t)255;
        return p;
    };

    // ---- fixed allocations (~82 MB) ----
    short* W1b = (short*)alloc(4l * 512 * 512 * 2);
    float* beff = (float*)alloc(4l * 512 * 4);
    short* Wqkvb = (short*)alloc(1536l * 512 * 2);
    float* bqkv = (float*)alloc(1536l * 4);
    short* wo_b = (short*)alloc(512l * 512 * 2);
    short* wff_b = (short*)alloc(512l * 512 * 2);
    short* w2_b = (short*)alloc(4l * 32 * 512 * 2);
    float* mean1 = (float*)alloc(512 * 4);
    float* rs1 = (float*)alloc(512 * 4);
    float* scale2 = (float*)alloc(2048 * 4);
    float* shift2 = (float*)alloc(2048 * 4);
    float* scale3 = (float*)alloc(128 * 4);
    float* shift3 = (float*)alloc(128 * 4);
    float* psum1 = (float*)alloc(256l * 512 * 4);
    float* psq1 = (float*)alloc(256l * 512 * 4);
    float* psum2 = (float*)alloc(128l * 2048 * 4);
    float* psq2 = (float*)alloc(128l * 2048 * 4);
    float* psum3 = (float*)alloc(256l * 128 * 4);
    float* psq3 = (float*)alloc(256l * 128 * 4);
    short* slotA = (short*)alloc(16384l * 2048 * 2);  // h -> t -> a1 (in-place)
    float* out_pre = (float*)alloc(16384l * 128 * 4);
    short* bufB = (short*)alloc(16384l * 2048 * 2);   // xb -> attn_o -> a2 (64 MB)

    // ---- qkv arena: NCq batch-rows; try full batch first, guarded fallback ----
    long NCq = 1024;
    for (long cand = 16384; cand >= 1024; cand >>= 1) {
        if (off + (size_t)cand * 12288 + (1u << 20) <= ws_size) { NCq = cand; break; }
    }
    short* qkv_c = (short*)alloc((size_t)NCq * 12288);
    short* xb = bufB;  // 16 MB input cast lives in bufB until E1 consumes it

    dim3 B256(256);

    // prep + x cast/stats
    hipLaunchKernelGGL(k_prep, dim3(678), B256, 0, stream,
                       wq, wk, wv, wo, wff, w2, bq, bk, bv,
                       Wqkvb, wo_b, wff_b, w2_b, bqkv);
    hipLaunchKernelGGL(k_statcast_x, dim3(256), B256, 0, stream, x, xb, psum1, psq1);

    // BN1 finalize + fold into E1 weights
    hipLaunchKernelGGL(k_finalize_meanrs, dim3(8), B256, 0, stream, psum1, psq1, 256, 512,
                       1.f / 16384.f, mean1, rs1);
    hipLaunchKernelGGL(k_fold_w1, dim3(2048), B256, 0, stream, w1, bn1_g, bn1_b, mean1, rs1, W1b, beff);

    // E1 + fused BN2 partial stats (xb in bufB; h -> slotA)
    hipLaunchKernelGGL(k_gemm_e1, dim3(128, 4, 4), B256, 0, stream,
                       xb, W1b, beff, slotA, psum2, psq2);

    // BN2 finalize + sigmoid -> t (in-place in slotA)
    hipLaunchKernelGGL(k_finalize_ss, dim3(32), B256, 0, stream, psum2, psq2, 128, 2048,
                       1.f / 16384.f, bn2_g, bn2_b, scale2, shift2);
    hipLaunchKernelGGL(k_bnsig, dim3(16384), B256, 0, stream, slotA, slotA, scale2, shift2);

    // ---- QKV + attention (full-batch if ws allows; attn_o -> bufB) ----
    long nch = 16384 / NCq;
    for (long c = 0; c < nch; ++c) {
        long r0 = c * NCq;
        const short* t_c = slotA + r0 * 2048;
        int gx = (int)(NCq * 4 / 128);

        hipLaunchKernelGGL((k_gemm_bt<128, 128, 2, 2, false, true>), dim3(gx, 12, 1), B256, 0, stream,
                           t_c, 0, 512, Wqkvb, 0, bqkv, 0,
                           qkv_c, (float*)nullptr, 0, 1536, (const short*)nullptr, 0, 512);

        hipLaunchKernelGGL(k_attn, dim3((int)(NCq / 4)), B256, 0, stream,
                           qkv_c, bufB + r0 * 2048);
    }

    // ---- full-batch tail ----
    // O-proj + bias + residual t, IN-PLACE over t (slotA) -> a1pre
    hipLaunchKernelGGL((k_gemm_bt<128, 128, 2, 2, true, true>), dim3(512, 4, 1), B256, 0, stream,
                       bufB, 0, 512, wo_b, 0, bo, 0,
                       slotA, (float*)nullptr, 0, 512, slotA, 512, 512);

    // LN1 in-place (slotA = a1)
    hipLaunchKernelGGL(k_ln, dim3(16384), B256, 0, stream, slotA, slotA, ln1_g, ln1_b);

    // FF + bias + residual a1 -> a2pre (bufB; attn data dead)
    hipLaunchKernelGGL((k_gemm_bt<128, 128, 2, 2, true, true>), dim3(512, 4, 1), B256, 0, stream,
                       slotA, 0, 512, wff_b, 0, bff, 0,
                       bufB, (float*)nullptr, 0, 512, slotA, 512, 512);

    // LN2 in-place (bufB = a2)
    hipLaunchKernelGGL(k_ln, dim3(16384), B256, 0, stream, bufB, bufB, ln2_g, ln2_b);

    // E2 + fused BN3 partial stats -> out_pre (f32), psum3[128 parts][128 cols]
    hipLaunchKernelGGL(k_gemm_e2, dim3(128, 1, 4), B256, 0, stream,
                       bufB, 512, 2048, w2_b, out_pre, 128, psum3, psq3);

    // BN3 finalize + sigmoid -> out
    hipLaunchKernelGGL(k_finalize_ss, dim3(2), B256, 0, stream, psum3, psq3, 128, 128,
                       1.f / 16384.f, bn3_g, bn3_b, scale3, shift3);
    hipLaunchKernelGGL(k_bn3sig, dim3(2048), B256, 0, stream, out_pre, out, scale3, shift3);
}